// Round 12
// baseline (48.779 us; speedup 1.0000x reference)
//
#include <hip/hip_runtime.h>

namespace {
constexpr int NPTS = 16384;
constexpr int CH   = 64;
constexpr int KNN  = 16;
constexpr int ROWS = 8 * NPTS;
constexpr float EPS = 1e-5f;
constexpr int NBLK = 2048;           // k_fused grid
constexpr int RBLK = 16;             // k_reduce grid
}

typedef __attribute__((ext_vector_type(8))) short  short8;
typedef __attribute__((ext_vector_type(4))) float  f32x4;
typedef __attribute__((ext_vector_type(4))) unsigned uint4v;
typedef __attribute__((ext_vector_type(2))) unsigned uint2v;
typedef __attribute__((ext_vector_type(4))) int    int4v;

static __device__ __forceinline__ unsigned pk_bf16(float lo, float hi) {
    unsigned r;
    asm("v_cvt_pk_bf16_f32 %0, %1, %2" : "=v"(r) : "v"(lo), "v"(hi));
    return r;
}

// Volatile packed 16-bit signed max (== relu(max) for bf16 with 0 seed).
#define PKM(D, A, B) asm volatile("v_pk_max_i16 %0, %1, %2" : "=v"(D) : "v"(A), "v"(B))

static __device__ __host__ __forceinline__ unsigned f2bf(float f) {
    unsigned u = __builtin_bit_cast(unsigned, f);
    return (u + 0x7fffu + ((u >> 16) & 1u)) >> 16;   // RNE
}

// W -> bf16 B-fragments (per-lane MFMA order).
static __device__ __forceinline__ void prep_wfrags(const float* __restrict__ W,
                                                   unsigned* __restrict__ wsb, int l)
{
    const int nq = l >> 4, nr = l & 15;
#pragma unroll
    for (int ct = 0; ct < 4; ++ct)
#pragma unroll
        for (int kh = 0; kh < 2; ++kh) {
            uint4v d;
#pragma unroll
            for (int dj = 0; dj < 4; ++dj) {
                const int k0 = kh * 32 + nq * 8 + dj * 2;
                unsigned lo = f2bf(W[(size_t)k0 * CH + ct * 16 + nr]);
                unsigned hi = f2bf(W[(size_t)(k0 + 1) * CH + ct * 16 + nr]);
                d[dj] = lo | (hi << 16);
            }
            ((uint4v*)wsb)[(ct * 2 + kh) * 64 + l] = d;
        }
}

// x (f32) -> bf16 rows of 128B, XCD-pinned (batch = blockIdx&7).
// CACHED loads: x is L3-resident across graph replays (r10 lesson).
__global__ __launch_bounds__(256)
void k_cvt(const float* __restrict__ x, unsigned* __restrict__ xb16,
           const float* __restrict__ W, unsigned* __restrict__ wsb)
{
    if (blockIdx.x == 0 && threadIdx.x < 64) prep_wfrags(W, wsb, threadIdx.x);
    const int batch = blockIdx.x & 7;
    const int chunk = blockIdx.x >> 3;
    const int lane8 = threadIdx.x & 7;
    const int rr    = threadIdx.x >> 3;
    const float*  xb = x    + (size_t)batch * NPTS * CH;
    unsigned*     ob = xb16 + (size_t)batch * NPTS * 32;
#pragma unroll
    for (int h = 0; h < 2; ++h) {
        const int row = chunk * 64 + h * 32 + rr;
        const f32x4* src = (const f32x4*)(xb + (size_t)row * CH + lane8 * 8);
        f32x4 v0 = src[0], v1 = src[1];
        uint4v d;
        d[0] = pk_bf16(v0[0], v0[1]);
        d[1] = pk_bf16(v0[2], v0[3]);
        d[2] = pk_bf16(v1[0], v1[1]);
        d[3] = pk_bf16(v1[2], v1[3]);
        *(uint4v*)(ob + (size_t)row * 32 + lane8 * 4) = d;
    }
}

// Main fused kernel. asm gather clause + two-step drain.
// NT y-stores: each 16-lane quarter writes one FULL 128B line (no
// amplification, unlike r6's 64B f32 segments) -> y stream no longer
// evicts the xb16 gather slab from the XCD L2.
__global__ __launch_bounds__(256)
void k_fused_bf16(const unsigned* __restrict__ xb16, const int* __restrict__ idx,
                  const unsigned* __restrict__ wsb, unsigned* __restrict__ yp,
                  float* __restrict__ partials)
{
    __shared__ __align__(16) ushort   Atile[4][16 * 64];  // per-wave, XOR-swizzled
    __shared__ __align__(16) int      Ibuf[4][256];       // per-wave 16x16 idx
    __shared__ __align__(16) unsigned Blds[2048];         // 8KB B-fragments
    __shared__ float bs1[64], bs2[64];

    const int lane  = threadIdx.x & 63;
    const int wave  = threadIdx.x >> 6;
    const int batch = blockIdx.x & 7;                     // XCD-aligned
    const int chunk = blockIdx.x >> 3;

    ((uint4v*)Blds)[threadIdx.x]       = ((const uint4v*)wsb)[threadIdx.x];
    ((uint4v*)Blds)[threadIdx.x + 256] = ((const uint4v*)wsb)[threadIdx.x + 256];
    if (threadIdx.x < 64)       bs1[threadIdx.x] = 0.f;
    else if (threadIdx.x < 128) bs2[threadIdx.x - 64] = 0.f;
    __syncthreads();

    const unsigned* __restrict__ xb = xb16 + (size_t)batch * NPTS * 32;
    const int*      __restrict__ ib = idx  + (size_t)batch * NPTS * KNN;
    unsigned*       __restrict__ yb = yp   + (size_t)batch * NPTS * 32;

    const int r0 = chunk * 64 + wave * 16;
    const int g8 = lane >> 3, c8 = lane & 7;
    const int c4 = lane & 15, qq = lane >> 4;
    const unsigned off16 = (unsigned)c8 * 16u;            // byte offset in 128B row

    // stage this tile's 256 indices (NT: idx is a pure stream)
    int4v iq = __builtin_nontemporal_load((const int4v*)(ib + (size_t)r0 * KNN) + lane);
    *(int4v*)&Ibuf[wave][lane * 4] = iq;

    // this lane-group's 32 row indices -> registers (broadcast ds_read_b128)
    const int4v* Ip = (const int4v*)&Ibuf[wave][0];
    int ia[16], ibx[16];
    *(int4v*)&ia[0]  = Ip[g8 * 4 + 0];       *(int4v*)&ia[4]  = Ip[g8 * 4 + 1];
    *(int4v*)&ia[8]  = Ip[g8 * 4 + 2];       *(int4v*)&ia[12] = Ip[g8 * 4 + 3];
    *(int4v*)&ibx[0] = Ip[(g8 + 8) * 4 + 0]; *(int4v*)&ibx[4] = Ip[(g8 + 8) * 4 + 1];
    *(int4v*)&ibx[8] = Ip[(g8 + 8) * 4 + 2]; *(int4v*)&ibx[12]= Ip[(g8 + 8) * 4 + 3];

    // issue ALL 32 gathers as one volatile clause (saddr + 32b voffset)
    uint4v va[16], vb[16];
#pragma unroll
    for (int j = 0; j < 16; ++j)
        asm volatile("global_load_dwordx4 %0, %1, %2"
                     : "=v"(va[j])
                     : "v"((unsigned)ia[j] * 128u + off16), "s"(xb));
#pragma unroll
    for (int j = 0; j < 16; ++j)
        asm volatile("global_load_dwordx4 %0, %1, %2"
                     : "=v"(vb[j])
                     : "v"((unsigned)ibx[j] * 128u + off16), "s"(xb));

    uint4v accA = {0, 0, 0, 0}, accB = {0, 0, 0, 0};      // seed 0 == relu

    // step 1: all va complete (16 vb still outstanding) -> reduce va under vb flight
    asm volatile("s_waitcnt vmcnt(16)" ::: "memory");
    __builtin_amdgcn_sched_barrier(0);
#pragma unroll
    for (int j = 0; j < 16; ++j) {
        PKM(accA[0], accA[0], va[j][0]); PKM(accA[1], accA[1], va[j][1]);
        PKM(accA[2], accA[2], va[j][2]); PKM(accA[3], accA[3], va[j][3]);
    }
    // step 2: drain vb
    asm volatile("s_waitcnt vmcnt(0)" ::: "memory");
    __builtin_amdgcn_sched_barrier(0);
#pragma unroll
    for (int j = 0; j < 16; ++j) {
        PKM(accB[0], accB[0], vb[j][0]); PKM(accB[1], accB[1], vb[j][1]);
        PKM(accB[2], accB[2], vb[j][2]); PKM(accB[3], accB[3], vb[j][3]);
    }

    // A-tile write (already packed bf16 in storage order), XOR-swizzled
    char* aw = (char*)&Atile[wave][0];
    *(uint4v*)(aw + ((g8 * 128 + c8 * 16) ^ (g8 << 4)))       = accA;
    *(uint4v*)(aw + (((g8 + 8) * 128 + c8 * 16) ^ (g8 << 4))) = accB;

    // A fragments: row = lane&15, k = (lane>>4)*8 + j (+32 for second)
    const int key = (c4 & 7) << 4;
    short8 a0 = *(const short8*)(aw + ((c4 * 128 + qq * 16) ^ key));
    short8 a1 = *(const short8*)(aw + ((c4 * 128 + 64 + qq * 16) ^ key));

    short8 bfr[8];
#pragma unroll
    for (int f = 0; f < 8; ++f)
        bfr[f] = __builtin_bit_cast(short8, ((const uint4v*)Blds)[f * 64 + lane]);

    f32x4 acc0 = {0,0,0,0}, acc1 = {0,0,0,0}, acc2 = {0,0,0,0}, acc3 = {0,0,0,0};
    acc0 = __builtin_amdgcn_mfma_f32_16x16x32_bf16(a0, bfr[0], acc0, 0, 0, 0);
    acc0 = __builtin_amdgcn_mfma_f32_16x16x32_bf16(a1, bfr[1], acc0, 0, 0, 0);
    acc1 = __builtin_amdgcn_mfma_f32_16x16x32_bf16(a0, bfr[2], acc1, 0, 0, 0);
    acc1 = __builtin_amdgcn_mfma_f32_16x16x32_bf16(a1, bfr[3], acc1, 0, 0, 0);
    acc2 = __builtin_amdgcn_mfma_f32_16x16x32_bf16(a0, bfr[4], acc2, 0, 0, 0);
    acc2 = __builtin_amdgcn_mfma_f32_16x16x32_bf16(a1, bfr[5], acc2, 0, 0, 0);
    acc3 = __builtin_amdgcn_mfma_f32_16x16x32_bf16(a0, bfr[6], acc3, 0, 0, 0);
    acc3 = __builtin_amdgcn_mfma_f32_16x16x32_bf16(a1, bfr[7], acc3, 0, 0, 0);

    // C/D: col = ct*16 + (lane&15), row = (lane>>4)*4 + reg  [HW-verified]
    // y-bf16 NT store: 16-lane quarter covers a full 128B line per row.
    unsigned* ypr = yb + (size_t)(r0 + qq * 4) * 32 + c4 * 2;
#pragma unroll
    for (int r = 0; r < 4; ++r) {
        uint2v pr;
        pr[0] = pk_bf16(acc0[r], acc1[r]);
        pr[1] = pk_bf16(acc2[r], acc3[r]);
        __builtin_nontemporal_store(pr, (uint2v*)(ypr + (size_t)r * 32));
    }

    // BN partial stats from f32 accumulators
#define DO_CT(CT, ACC)                                                              \
    {                                                                               \
        float s1 = (ACC[0] + ACC[1]) + (ACC[2] + ACC[3]);                           \
        float s2 = (ACC[0]*ACC[0] + ACC[1]*ACC[1]) + (ACC[2]*ACC[2] + ACC[3]*ACC[3]); \
        s1 += __shfl_xor(s1, 16); s1 += __shfl_xor(s1, 32);                         \
        s2 += __shfl_xor(s2, 16); s2 += __shfl_xor(s2, 32);                         \
        if (lane < 16) {                                                            \
            atomicAdd(&bs1[CT * 16 + lane], s1);                                    \
            atomicAdd(&bs2[CT * 16 + lane], s2);                                    \
        }                                                                           \
    }
    DO_CT(0, acc0) DO_CT(1, acc1) DO_CT(2, acc2) DO_CT(3, acc3)
#undef DO_CT

    __syncthreads();
    // per-block partials: coalesced 512B store, NO device-scope atomics
    if (threadIdx.x < 128)
        partials[(size_t)blockIdx.x * 128 + threadIdx.x] =
            (threadIdx.x < 64) ? bs1[threadIdx.x] : bs2[threadIdx.x - 64];
}

// partials[2048][128] -> partial2[16][128]
__global__ __launch_bounds__(256)
void k_reduce(const float* __restrict__ partials, float* __restrict__ partial2)
{
    const int t = threadIdx.x;
    const int c = t & 127, h = t >> 7;
    const float* p = partials + ((size_t)blockIdx.x * 128 + h * 64) * 128 + c;
    float s = 0.f;
#pragma unroll 8
    for (int r = 0; r < 64; ++r) s += p[(size_t)r * 128];
    __shared__ float red[256];
    red[t] = s;
    __syncthreads();
    if (t < 128) partial2[(size_t)blockIdx.x * 128 + t] = red[t] + red[t + 128];
}

// bf16-y normalize: read uint2 (coalesced), unpack 4 cols, write 4 dword-
// segments (64B each). One task per (row, c4).
__global__ __launch_bounds__(256)
void k_norm_bf16(const unsigned* __restrict__ yp, float* __restrict__ y,
                 const float* __restrict__ partial2,
                 const float* __restrict__ gamma, const float* __restrict__ beta)
{
    __shared__ float s[CH], b[CH];
    if (threadIdx.x < CH) {
        const int l = threadIdx.x;
        float s1 = 0.f, s2 = 0.f;
#pragma unroll
        for (int k = 0; k < RBLK; ++k) {
            s1 += partial2[k * 128 + l];
            s2 += partial2[k * 128 + 64 + l];
        }
        const float inv_n = 1.0f / (float)ROWS;
        float mean = s1 * inv_n;
        float var  = s2 * inv_n - mean * mean;
        float sc   = gamma[l] * rsqrtf(var + EPS);
        s[l] = sc;
        b[l] = beta[l] - mean * sc;
    }
    __syncthreads();

    const size_t ntot = (size_t)ROWS * 16;
    size_t i = (size_t)blockIdx.x * blockDim.x + threadIdx.x;
    const size_t stride = (size_t)gridDim.x * blockDim.x;
    for (; i < ntot; i += stride) {
        const size_t row = i >> 4;
        const int c4 = (int)i & 15;
        uint2v p = *(const uint2v*)(yp + row * 32 + c4 * 2);
        float v0 = __uint_as_float(p[0] << 16);
        float v1 = __uint_as_float(p[0] & 0xffff0000u);
        float v2 = __uint_as_float(p[1] << 16);
        float v3 = __uint_as_float(p[1] & 0xffff0000u);
        float* yr = y + row * CH;
        yr[c4]      = fmaf(v0, s[c4],      b[c4]);
        yr[c4 + 16] = fmaf(v1, s[c4 + 16], b[c4 + 16]);
        yr[c4 + 32] = fmaf(v2, s[c4 + 32], b[c4 + 32]);
        yr[c4 + 48] = fmaf(v3, s[c4 + 48], b[c4 + 48]);
    }
}

// ---- fallback path (ws too small): round-2 f32 kernel + atomic stats ----
__global__ __launch_bounds__(64)
void k_prep_fb(const float* __restrict__ W, unsigned* __restrict__ wsb,
               float* __restrict__ stats)
{
    if (threadIdx.x < 64) {
        stats[threadIdx.x] = 0.f;
        stats[64 + threadIdx.x] = 0.f;
        prep_wfrags(W, wsb, threadIdx.x);
    }
}

__global__ __launch_bounds__(256)
void k_fused_f32(const float* __restrict__ x, const int* __restrict__ idx,
                 const unsigned* __restrict__ wsb, float* __restrict__ y,
                 float* __restrict__ stats)
{
    __shared__ __align__(16) ushort Atile[4][16 * 64];
    __shared__ __align__(16) int    Ibuf[4][256];
    __shared__ float bs1[64], bs2[64];

    const int lane  = threadIdx.x & 63;
    const int wave  = threadIdx.x >> 6;
    const int batch = blockIdx.x & 7;
    const int chunk = blockIdx.x >> 3;

    if (threadIdx.x < 64)       bs1[threadIdx.x] = 0.f;
    else if (threadIdx.x < 128) bs2[threadIdx.x - 64] = 0.f;
    __syncthreads();

    const int r0 = chunk * 64 + wave * 16;
    const float* __restrict__ xb = x   + (size_t)batch * NPTS * CH;
    const int*   __restrict__ ib = idx + (size_t)batch * NPTS * KNN;
    float*       __restrict__ yb = y   + (size_t)batch * NPTS * CH;

    const int c4 = lane & 15;
    const int qq = lane >> 4;

    int4v iq = ((const int4v*)(ib + (size_t)r0 * KNN))[lane];
    *(int4v*)&Ibuf[wave][lane * 4] = iq;

    short8 bfr[8];
#pragma unroll
    for (int f = 0; f < 8; ++f)
        bfr[f] = __builtin_bit_cast(short8, ((const uint4v*)wsb)[f * 64 + lane]);

    char* aw = (char*)&Atile[wave][0];
    const f32x4* xb4 = (const f32x4*)xb;

#pragma unroll
    for (int g = 0; g < 4; ++g) {
        const int row = 4 * g + qq;
        const int* ip = &Ibuf[wave][row * KNN];
        f32x4 acc = {0.f, 0.f, 0.f, 0.f};
#pragma unroll
        for (int j = 0; j < KNN; ++j) {
            const int n = ip[j];
            f32x4 v = xb4[n * 16 + c4];
            acc[0] = fmaxf(acc[0], v[0]);
            acc[1] = fmaxf(acc[1], v[1]);
            acc[2] = fmaxf(acc[2], v[2]);
            acc[3] = fmaxf(acc[3], v[3]);
        }
        uint2v pw;
        pw[0] = pk_bf16(acc[0], acc[1]);
        pw[1] = pk_bf16(acc[2], acc[3]);
        const int wb = ((row * 128) + c4 * 8) ^ ((row & 7) << 4);
        *(uint2v*)(aw + wb) = pw;
    }

    const int key = (c4 & 7) << 4;
    short8 a0 = *(const short8*)(aw + ((c4 * 128 + qq * 16) ^ key));
    short8 a1 = *(const short8*)(aw + ((c4 * 128 + 64 + qq * 16) ^ key));

    f32x4 acc0 = {0,0,0,0}, acc1 = {0,0,0,0}, acc2 = {0,0,0,0}, acc3 = {0,0,0,0};
    acc0 = __builtin_amdgcn_mfma_f32_16x16x32_bf16(a0, bfr[0], acc0, 0, 0, 0);
    acc0 = __builtin_amdgcn_mfma_f32_16x16x32_bf16(a1, bfr[1], acc0, 0, 0, 0);
    acc1 = __builtin_amdgcn_mfma_f32_16x16x32_bf16(a0, bfr[2], acc1, 0, 0, 0);
    acc1 = __builtin_amdgcn_mfma_f32_16x16x32_bf16(a1, bfr[3], acc1, 0, 0, 0);
    acc2 = __builtin_amdgcn_mfma_f32_16x16x32_bf16(a0, bfr[4], acc2, 0, 0, 0);
    acc2 = __builtin_amdgcn_mfma_f32_16x16x32_bf16(a1, bfr[5], acc2, 0, 0, 0);
    acc3 = __builtin_amdgcn_mfma_f32_16x16x32_bf16(a0, bfr[6], acc3, 0, 0, 0);
    acc3 = __builtin_amdgcn_mfma_f32_16x16x32_bf16(a1, bfr[7], acc3, 0, 0, 0);

    float* yrow = yb + (size_t)(r0 + qq * 4) * CH + c4;
#define DO_CT(CT, ACC)                                                              \
    {                                                                               \
        yrow[0 * CH + CT * 16] = ACC[0];                                            \
        yrow[1 * CH + CT * 16] = ACC[1];                                            \
        yrow[2 * CH + CT * 16] = ACC[2];                                            \
        yrow[3 * CH + CT * 16] = ACC[3];                                            \
        float s1 = (ACC[0] + ACC[1]) + (ACC[2] + ACC[3]);                           \
        float s2 = (ACC[0]*ACC[0] + ACC[1]*ACC[1]) + (ACC[2]*ACC[2] + ACC[3]*ACC[3]); \
        s1 += __shfl_xor(s1, 16); s1 += __shfl_xor(s1, 32);                         \
        s2 += __shfl_xor(s2, 16); s2 += __shfl_xor(s2, 32);                         \
        if (lane < 16) {                                                            \
            atomicAdd(&bs1[CT * 16 + lane], s1);                                    \
            atomicAdd(&bs2[CT * 16 + lane], s2);                                    \
        }                                                                           \
    }
    DO_CT(0, acc0) DO_CT(1, acc1) DO_CT(2, acc2) DO_CT(3, acc3)
#undef DO_CT

    __syncthreads();
    if (threadIdx.x < 64)        atomicAdd(&stats[threadIdx.x], bs1[threadIdx.x]);
    else if (threadIdx.x < 128)  atomicAdd(&stats[threadIdx.x], bs2[threadIdx.x - 64]);
}

// fallback normalize: in-place on f32 y, stats[128] source
__global__ __launch_bounds__(256)
void k_norm_f32(float* __restrict__ y, const float* __restrict__ stats,
                const float* __restrict__ gamma, const float* __restrict__ beta)
{
    __shared__ float s[CH], b[CH];
    if (threadIdx.x < CH) {
        const int l = threadIdx.x;
        const float inv_n = 1.0f / (float)ROWS;
        float mean = stats[l] * inv_n;
        float var  = stats[64 + l] * inv_n - mean * mean;
        float sc   = gamma[l] * rsqrtf(var + EPS);
        s[l] = sc;
        b[l] = beta[l] - mean * sc;
    }
    __syncthreads();

    f32x4* p = (f32x4*)y;
    const size_t ntot = (size_t)ROWS * CH / 4;
    size_t i = (size_t)blockIdx.x * blockDim.x + threadIdx.x;
    const size_t stride = (size_t)gridDim.x * blockDim.x;
    for (; i < ntot; i += stride) {
        f32x4 v = p[i];
        const int c0 = ((int)i & 15) * 4;
        v[0] = fmaf(v[0], s[c0],     b[c0]);
        v[1] = fmaf(v[1], s[c0 + 1], b[c0 + 1]);
        v[2] = fmaf(v[2], s[c0 + 2], b[c0 + 2]);
        v[3] = fmaf(v[3], s[c0 + 3], b[c0 + 3]);
        p[i] = v;
    }
}

extern "C" void kernel_launch(void* const* d_in, const int* in_sizes, int n_in,
                              void* d_out, int out_size, void* d_ws, size_t ws_size,
                              hipStream_t stream)
{
    const float* x     = (const float*)d_in[0];
    const int*   idx   = (const int*)d_in[1];
    const float* W     = (const float*)d_in[2];
    const float* gamma = (const float*)d_in[3];
    const float* beta  = (const float*)d_in[4];

    float*    y     = (float*)d_out;
    float*    stats = (float*)d_ws;                       // fallback only
    unsigned* wsb   = (unsigned*)(stats + 256);           // 8KB B-fragments
    char*     base  = (char*)d_ws + 16384;
    unsigned* xb16  = (unsigned*)base;                                   // 16.8MB
    float*    parts = (float*)(base + (size_t)ROWS * CH * 2);            // 1MB
    float*    part2 = parts + (size_t)NBLK * 128;                        // 8KB
    unsigned* yp    = (unsigned*)(part2 + (size_t)RBLK * 128);           // 16.8MB

    const size_t need = 16384 + (size_t)ROWS * CH * 2
                      + (size_t)NBLK * 128 * 4 + (size_t)RBLK * 128 * 4
                      + (size_t)ROWS * CH * 2;

    if (ws_size >= need) {
        k_cvt<<<dim3(2048), dim3(256), 0, stream>>>(x, xb16, W, wsb);
        k_fused_bf16<<<dim3(NBLK), dim3(256), 0, stream>>>(xb16, idx, wsb, yp, parts);
        k_reduce<<<dim3(RBLK), dim3(256), 0, stream>>>(parts, part2);
        k_norm_bf16<<<dim3(2048), dim3(256), 0, stream>>>(yp, y, part2, gamma, beta);
    } else {
        k_prep_fb<<<dim3(1), dim3(64), 0, stream>>>(W, wsb, stats);
        k_fused_f32<<<dim3(2048), dim3(256), 0, stream>>>(x, idx, wsb, y, stats);
        k_norm_f32<<<dim3(2048), dim3(256), 0, stream>>>(y, stats, gamma, beta);
    }
}

// Round 13
// 44.258 us; speedup vs baseline: 1.1022x; 1.1022x over previous
//
#include <hip/hip_runtime.h>

namespace {
constexpr int NPTS = 16384;
constexpr int CH   = 64;
constexpr int KNN  = 16;
constexpr int ROWS = 8 * NPTS;
constexpr float EPS = 1e-5f;
constexpr int NBLK = 2048;           // k_fused grid
constexpr int RBLK = 16;             // k_reduce grid
}

typedef __attribute__((ext_vector_type(8))) short  short8;
typedef __attribute__((ext_vector_type(4))) float  f32x4;
typedef __attribute__((ext_vector_type(4))) unsigned uint4v;
typedef __attribute__((ext_vector_type(2))) unsigned uint2v;
typedef __attribute__((ext_vector_type(4))) int    int4v;

static __device__ __forceinline__ unsigned pk_bf16(float lo, float hi) {
    unsigned r;
    asm("v_cvt_pk_bf16_f32 %0, %1, %2" : "=v"(r) : "v"(lo), "v"(hi));
    return r;
}

// Volatile packed 16-bit signed max (== relu(max) for bf16 with 0 seed).
#define PKM(D, A, B) asm volatile("v_pk_max_i16 %0, %1, %2" : "=v"(D) : "v"(A), "v"(B))

static __device__ __host__ __forceinline__ unsigned f2bf(float f) {
    unsigned u = __builtin_bit_cast(unsigned, f);
    return (u + 0x7fffu + ((u >> 16) & 1u)) >> 16;   // RNE
}

// W -> bf16 B-fragments (per-lane MFMA order).
static __device__ __forceinline__ void prep_wfrags(const float* __restrict__ W,
                                                   unsigned* __restrict__ wsb, int l)
{
    const int nq = l >> 4, nr = l & 15;
#pragma unroll
    for (int ct = 0; ct < 4; ++ct)
#pragma unroll
        for (int kh = 0; kh < 2; ++kh) {
            uint4v d;
#pragma unroll
            for (int dj = 0; dj < 4; ++dj) {
                const int k0 = kh * 32 + nq * 8 + dj * 2;
                unsigned lo = f2bf(W[(size_t)k0 * CH + ct * 16 + nr]);
                unsigned hi = f2bf(W[(size_t)(k0 + 1) * CH + ct * 16 + nr]);
                d[dj] = lo | (hi << 16);
            }
            ((uint4v*)wsb)[(ct * 2 + kh) * 64 + l] = d;
        }
}

// x (f32) -> bf16 rows of 128B, XCD-pinned (batch = blockIdx&7).
// CACHED loads everywhere: all read-once inputs are L3-resident across graph
// replays; NT loads force the HBM path and cost 2-3us (r10/r12 lessons).
__global__ __launch_bounds__(256)
void k_cvt(const float* __restrict__ x, unsigned* __restrict__ xb16,
           const float* __restrict__ W, unsigned* __restrict__ wsb)
{
    if (blockIdx.x == 0 && threadIdx.x < 64) prep_wfrags(W, wsb, threadIdx.x);
    const int batch = blockIdx.x & 7;
    const int chunk = blockIdx.x >> 3;
    const int lane8 = threadIdx.x & 7;
    const int rr    = threadIdx.x >> 3;
    const float*  xb = x    + (size_t)batch * NPTS * CH;
    unsigned*     ob = xb16 + (size_t)batch * NPTS * 32;
#pragma unroll
    for (int h = 0; h < 2; ++h) {
        const int row = chunk * 64 + h * 32 + rr;
        const f32x4* src = (const f32x4*)(xb + (size_t)row * CH + lane8 * 8);
        f32x4 v0 = src[0], v1 = src[1];
        uint4v d;
        d[0] = pk_bf16(v0[0], v0[1]);
        d[1] = pk_bf16(v0[2], v0[3]);
        d[2] = pk_bf16(v1[0], v1[1]);
        d[3] = pk_bf16(v1[2], v1[3]);
        *(uint4v*)(ob + (size_t)row * 32 + lane8 * 4) = d;
    }
}

// Main fused kernel (r11 structure). asm gather clause + two-step drain.
// Cached y-stores (NT regressed +2.2us, r12) and cached idx load (NT on an
// L3-resident stream adds HBM latency to the per-wave critical path).
__global__ __launch_bounds__(256)
void k_fused_bf16(const unsigned* __restrict__ xb16, const int* __restrict__ idx,
                  const unsigned* __restrict__ wsb, unsigned* __restrict__ yp,
                  float* __restrict__ partials)
{
    __shared__ __align__(16) ushort   Atile[4][16 * 64];  // per-wave, XOR-swizzled
    __shared__ __align__(16) int      Ibuf[4][256];       // per-wave 16x16 idx
    __shared__ __align__(16) unsigned Blds[2048];         // 8KB B-fragments
    __shared__ float bs1[64], bs2[64];

    const int lane  = threadIdx.x & 63;
    const int wave  = threadIdx.x >> 6;
    const int batch = blockIdx.x & 7;                     // XCD-aligned
    const int chunk = blockIdx.x >> 3;

    ((uint4v*)Blds)[threadIdx.x]       = ((const uint4v*)wsb)[threadIdx.x];
    ((uint4v*)Blds)[threadIdx.x + 256] = ((const uint4v*)wsb)[threadIdx.x + 256];
    if (threadIdx.x < 64)       bs1[threadIdx.x] = 0.f;
    else if (threadIdx.x < 128) bs2[threadIdx.x - 64] = 0.f;
    __syncthreads();

    const unsigned* __restrict__ xb = xb16 + (size_t)batch * NPTS * 32;
    const int*      __restrict__ ib = idx  + (size_t)batch * NPTS * KNN;
    unsigned*       __restrict__ yb = yp   + (size_t)batch * NPTS * 32;

    const int r0 = chunk * 64 + wave * 16;
    const int g8 = lane >> 3, c8 = lane & 7;
    const int c4 = lane & 15, qq = lane >> 4;
    const unsigned off16 = (unsigned)c8 * 16u;            // byte offset in 128B row

    // stage this tile's 256 indices (cached: idx is L3-resident across replays)
    int4v iq = ((const int4v*)(ib + (size_t)r0 * KNN))[lane];
    *(int4v*)&Ibuf[wave][lane * 4] = iq;

    // this lane-group's 32 row indices -> registers (broadcast ds_read_b128)
    const int4v* Ip = (const int4v*)&Ibuf[wave][0];
    int ia[16], ibx[16];
    *(int4v*)&ia[0]  = Ip[g8 * 4 + 0];       *(int4v*)&ia[4]  = Ip[g8 * 4 + 1];
    *(int4v*)&ia[8]  = Ip[g8 * 4 + 2];       *(int4v*)&ia[12] = Ip[g8 * 4 + 3];
    *(int4v*)&ibx[0] = Ip[(g8 + 8) * 4 + 0]; *(int4v*)&ibx[4] = Ip[(g8 + 8) * 4 + 1];
    *(int4v*)&ibx[8] = Ip[(g8 + 8) * 4 + 2]; *(int4v*)&ibx[12]= Ip[(g8 + 8) * 4 + 3];

    // issue ALL 32 gathers as one volatile clause (saddr + 32b voffset)
    uint4v va[16], vb[16];
#pragma unroll
    for (int j = 0; j < 16; ++j)
        asm volatile("global_load_dwordx4 %0, %1, %2"
                     : "=v"(va[j])
                     : "v"((unsigned)ia[j] * 128u + off16), "s"(xb));
#pragma unroll
    for (int j = 0; j < 16; ++j)
        asm volatile("global_load_dwordx4 %0, %1, %2"
                     : "=v"(vb[j])
                     : "v"((unsigned)ibx[j] * 128u + off16), "s"(xb));

    uint4v accA = {0, 0, 0, 0}, accB = {0, 0, 0, 0};      // seed 0 == relu

    // step 1: all va complete (16 vb still outstanding) -> reduce va under vb flight
    asm volatile("s_waitcnt vmcnt(16)" ::: "memory");
    __builtin_amdgcn_sched_barrier(0);
#pragma unroll
    for (int j = 0; j < 16; ++j) {
        PKM(accA[0], accA[0], va[j][0]); PKM(accA[1], accA[1], va[j][1]);
        PKM(accA[2], accA[2], va[j][2]); PKM(accA[3], accA[3], va[j][3]);
    }
    // step 2: drain vb
    asm volatile("s_waitcnt vmcnt(0)" ::: "memory");
    __builtin_amdgcn_sched_barrier(0);
#pragma unroll
    for (int j = 0; j < 16; ++j) {
        PKM(accB[0], accB[0], vb[j][0]); PKM(accB[1], accB[1], vb[j][1]);
        PKM(accB[2], accB[2], vb[j][2]); PKM(accB[3], accB[3], vb[j][3]);
    }

    // A-tile write (already packed bf16 in storage order), XOR-swizzled
    char* aw = (char*)&Atile[wave][0];
    *(uint4v*)(aw + ((g8 * 128 + c8 * 16) ^ (g8 << 4)))       = accA;
    *(uint4v*)(aw + (((g8 + 8) * 128 + c8 * 16) ^ (g8 << 4))) = accB;

    // A fragments: row = lane&15, k = (lane>>4)*8 + j (+32 for second)
    const int key = (c4 & 7) << 4;
    short8 a0 = *(const short8*)(aw + ((c4 * 128 + qq * 16) ^ key));
    short8 a1 = *(const short8*)(aw + ((c4 * 128 + 64 + qq * 16) ^ key));

    short8 bfr[8];
#pragma unroll
    for (int f = 0; f < 8; ++f)
        bfr[f] = __builtin_bit_cast(short8, ((const uint4v*)Blds)[f * 64 + lane]);

    f32x4 acc0 = {0,0,0,0}, acc1 = {0,0,0,0}, acc2 = {0,0,0,0}, acc3 = {0,0,0,0};
    acc0 = __builtin_amdgcn_mfma_f32_16x16x32_bf16(a0, bfr[0], acc0, 0, 0, 0);
    acc0 = __builtin_amdgcn_mfma_f32_16x16x32_bf16(a1, bfr[1], acc0, 0, 0, 0);
    acc1 = __builtin_amdgcn_mfma_f32_16x16x32_bf16(a0, bfr[2], acc1, 0, 0, 0);
    acc1 = __builtin_amdgcn_mfma_f32_16x16x32_bf16(a1, bfr[3], acc1, 0, 0, 0);
    acc2 = __builtin_amdgcn_mfma_f32_16x16x32_bf16(a0, bfr[4], acc2, 0, 0, 0);
    acc2 = __builtin_amdgcn_mfma_f32_16x16x32_bf16(a1, bfr[5], acc2, 0, 0, 0);
    acc3 = __builtin_amdgcn_mfma_f32_16x16x32_bf16(a0, bfr[6], acc3, 0, 0, 0);
    acc3 = __builtin_amdgcn_mfma_f32_16x16x32_bf16(a1, bfr[7], acc3, 0, 0, 0);

    // C/D: col = ct*16 + (lane&15), row = (lane>>4)*4 + reg  [HW-verified]
    // y-bf16 cached store: uint2 {pk(acc0,acc1), pk(acc2,acc3)} at [row][c4][2].
    unsigned* ypr = yb + (size_t)(r0 + qq * 4) * 32 + c4 * 2;
#pragma unroll
    for (int r = 0; r < 4; ++r) {
        uint2v pr;
        pr[0] = pk_bf16(acc0[r], acc1[r]);
        pr[1] = pk_bf16(acc2[r], acc3[r]);
        *(uint2v*)(ypr + (size_t)r * 32) = pr;
    }

    // BN partial stats from f32 accumulators
#define DO_CT(CT, ACC)                                                              \
    {                                                                               \
        float s1 = (ACC[0] + ACC[1]) + (ACC[2] + ACC[3]);                           \
        float s2 = (ACC[0]*ACC[0] + ACC[1]*ACC[1]) + (ACC[2]*ACC[2] + ACC[3]*ACC[3]); \
        s1 += __shfl_xor(s1, 16); s1 += __shfl_xor(s1, 32);                         \
        s2 += __shfl_xor(s2, 16); s2 += __shfl_xor(s2, 32);                         \
        if (lane < 16) {                                                            \
            atomicAdd(&bs1[CT * 16 + lane], s1);                                    \
            atomicAdd(&bs2[CT * 16 + lane], s2);                                    \
        }                                                                           \
    }
    DO_CT(0, acc0) DO_CT(1, acc1) DO_CT(2, acc2) DO_CT(3, acc3)
#undef DO_CT

    __syncthreads();
    // per-block partials: coalesced 512B store, NO device-scope atomics
    if (threadIdx.x < 128)
        partials[(size_t)blockIdx.x * 128 + threadIdx.x] =
            (threadIdx.x < 64) ? bs1[threadIdx.x] : bs2[threadIdx.x - 64];
}

// partials[2048][128] -> partial2[16][128]
__global__ __launch_bounds__(256)
void k_reduce(const float* __restrict__ partials, float* __restrict__ partial2)
{
    const int t = threadIdx.x;
    const int c = t & 127, h = t >> 7;
    const float* p = partials + ((size_t)blockIdx.x * 128 + h * 64) * 128 + c;
    float s = 0.f;
#pragma unroll 8
    for (int r = 0; r < 64; ++r) s += p[(size_t)r * 128];
    __shared__ float red[256];
    red[t] = s;
    __syncthreads();
    if (t < 128) partial2[(size_t)blockIdx.x * 128 + t] = red[t] + red[t + 128];
}

// bf16-y normalize: read uint2 (coalesced), unpack 4 cols, write 4 dword-
// segments (64B each). One task per (row, c4).
__global__ __launch_bounds__(256)
void k_norm_bf16(const unsigned* __restrict__ yp, float* __restrict__ y,
                 const float* __restrict__ partial2,
                 const float* __restrict__ gamma, const float* __restrict__ beta)
{
    __shared__ float s[CH], b[CH];
    if (threadIdx.x < CH) {
        const int l = threadIdx.x;
        float s1 = 0.f, s2 = 0.f;
#pragma unroll
        for (int k = 0; k < RBLK; ++k) {
            s1 += partial2[k * 128 + l];
            s2 += partial2[k * 128 + 64 + l];
        }
        const float inv_n = 1.0f / (float)ROWS;
        float mean = s1 * inv_n;
        float var  = s2 * inv_n - mean * mean;
        float sc   = gamma[l] * rsqrtf(var + EPS);
        s[l] = sc;
        b[l] = beta[l] - mean * sc;
    }
    __syncthreads();

    const size_t ntot = (size_t)ROWS * 16;
    size_t i = (size_t)blockIdx.x * blockDim.x + threadIdx.x;
    const size_t stride = (size_t)gridDim.x * blockDim.x;
    for (; i < ntot; i += stride) {
        const size_t row = i >> 4;
        const int c4 = (int)i & 15;
        uint2v p = *(const uint2v*)(yp + row * 32 + c4 * 2);
        float v0 = __uint_as_float(p[0] << 16);
        float v1 = __uint_as_float(p[0] & 0xffff0000u);
        float v2 = __uint_as_float(p[1] << 16);
        float v3 = __uint_as_float(p[1] & 0xffff0000u);
        float* yr = y + row * CH;
        yr[c4]      = fmaf(v0, s[c4],      b[c4]);
        yr[c4 + 16] = fmaf(v1, s[c4 + 16], b[c4 + 16]);
        yr[c4 + 32] = fmaf(v2, s[c4 + 32], b[c4 + 32]);
        yr[c4 + 48] = fmaf(v3, s[c4 + 48], b[c4 + 48]);
    }
}

// ---- fallback path (ws too small): round-2 f32 kernel + atomic stats ----
__global__ __launch_bounds__(64)
void k_prep_fb(const float* __restrict__ W, unsigned* __restrict__ wsb,
               float* __restrict__ stats)
{
    if (threadIdx.x < 64) {
        stats[threadIdx.x] = 0.f;
        stats[64 + threadIdx.x] = 0.f;
        prep_wfrags(W, wsb, threadIdx.x);
    }
}

__global__ __launch_bounds__(256)
void k_fused_f32(const float* __restrict__ x, const int* __restrict__ idx,
                 const unsigned* __restrict__ wsb, float* __restrict__ y,
                 float* __restrict__ stats)
{
    __shared__ __align__(16) ushort Atile[4][16 * 64];
    __shared__ __align__(16) int    Ibuf[4][256];
    __shared__ float bs1[64], bs2[64];

    const int lane  = threadIdx.x & 63;
    const int wave  = threadIdx.x >> 6;
    const int batch = blockIdx.x & 7;
    const int chunk = blockIdx.x >> 3;

    if (threadIdx.x < 64)       bs1[threadIdx.x] = 0.f;
    else if (threadIdx.x < 128) bs2[threadIdx.x - 64] = 0.f;
    __syncthreads();

    const int r0 = chunk * 64 + wave * 16;
    const float* __restrict__ xb = x   + (size_t)batch * NPTS * CH;
    const int*   __restrict__ ib = idx + (size_t)batch * NPTS * KNN;
    float*       __restrict__ yb = y   + (size_t)batch * NPTS * CH;

    const int c4 = lane & 15;
    const int qq = lane >> 4;

    int4v iq = ((const int4v*)(ib + (size_t)r0 * KNN))[lane];
    *(int4v*)&Ibuf[wave][lane * 4] = iq;

    short8 bfr[8];
#pragma unroll
    for (int f = 0; f < 8; ++f)
        bfr[f] = __builtin_bit_cast(short8, ((const uint4v*)wsb)[f * 64 + lane]);

    char* aw = (char*)&Atile[wave][0];
    const f32x4* xb4 = (const f32x4*)xb;

#pragma unroll
    for (int g = 0; g < 4; ++g) {
        const int row = 4 * g + qq;
        const int* ip = &Ibuf[wave][row * KNN];
        f32x4 acc = {0.f, 0.f, 0.f, 0.f};
#pragma unroll
        for (int j = 0; j < KNN; ++j) {
            const int n = ip[j];
            f32x4 v = xb4[n * 16 + c4];
            acc[0] = fmaxf(acc[0], v[0]);
            acc[1] = fmaxf(acc[1], v[1]);
            acc[2] = fmaxf(acc[2], v[2]);
            acc[3] = fmaxf(acc[3], v[3]);
        }
        uint2v pw;
        pw[0] = pk_bf16(acc[0], acc[1]);
        pw[1] = pk_bf16(acc[2], acc[3]);
        const int wb = ((row * 128) + c4 * 8) ^ ((row & 7) << 4);
        *(uint2v*)(aw + wb) = pw;
    }

    const int key = (c4 & 7) << 4;
    short8 a0 = *(const short8*)(aw + ((c4 * 128 + qq * 16) ^ key));
    short8 a1 = *(const short8*)(aw + ((c4 * 128 + 64 + qq * 16) ^ key));

    f32x4 acc0 = {0,0,0,0}, acc1 = {0,0,0,0}, acc2 = {0,0,0,0}, acc3 = {0,0,0,0};
    acc0 = __builtin_amdgcn_mfma_f32_16x16x32_bf16(a0, bfr[0], acc0, 0, 0, 0);
    acc0 = __builtin_amdgcn_mfma_f32_16x16x32_bf16(a1, bfr[1], acc0, 0, 0, 0);
    acc1 = __builtin_amdgcn_mfma_f32_16x16x32_bf16(a0, bfr[2], acc1, 0, 0, 0);
    acc1 = __builtin_amdgcn_mfma_f32_16x16x32_bf16(a1, bfr[3], acc1, 0, 0, 0);
    acc2 = __builtin_amdgcn_mfma_f32_16x16x32_bf16(a0, bfr[4], acc2, 0, 0, 0);
    acc2 = __builtin_amdgcn_mfma_f32_16x16x32_bf16(a1, bfr[5], acc2, 0, 0, 0);
    acc3 = __builtin_amdgcn_mfma_f32_16x16x32_bf16(a0, bfr[6], acc3, 0, 0, 0);
    acc3 = __builtin_amdgcn_mfma_f32_16x16x32_bf16(a1, bfr[7], acc3, 0, 0, 0);

    float* yrow = yb + (size_t)(r0 + qq * 4) * CH + c4;
#define DO_CT(CT, ACC)                                                              \
    {                                                                               \
        yrow[0 * CH + CT * 16] = ACC[0];                                            \
        yrow[1 * CH + CT * 16] = ACC[1];                                            \
        yrow[2 * CH + CT * 16] = ACC[2];                                            \
        yrow[3 * CH + CT * 16] = ACC[3];                                            \
        float s1 = (ACC[0] + ACC[1]) + (ACC[2] + ACC[3]);                           \
        float s2 = (ACC[0]*ACC[0] + ACC[1]*ACC[1]) + (ACC[2]*ACC[2] + ACC[3]*ACC[3]); \
        s1 += __shfl_xor(s1, 16); s1 += __shfl_xor(s1, 32);                         \
        s2 += __shfl_xor(s2, 16); s2 += __shfl_xor(s2, 32);                         \
        if (lane < 16) {                                                            \
            atomicAdd(&bs1[CT * 16 + lane], s1);                                    \
            atomicAdd(&bs2[CT * 16 + lane], s2);                                    \
        }                                                                           \
    }
    DO_CT(0, acc0) DO_CT(1, acc1) DO_CT(2, acc2) DO_CT(3, acc3)
#undef DO_CT

    __syncthreads();
    if (threadIdx.x < 64)        atomicAdd(&stats[threadIdx.x], bs1[threadIdx.x]);
    else if (threadIdx.x < 128)  atomicAdd(&stats[threadIdx.x], bs2[threadIdx.x - 64]);
}

// fallback normalize: in-place on f32 y, stats[128] source
__global__ __launch_bounds__(256)
void k_norm_f32(float* __restrict__ y, const float* __restrict__ stats,
                const float* __restrict__ gamma, const float* __restrict__ beta)
{
    __shared__ float s[CH], b[CH];
    if (threadIdx.x < CH) {
        const int l = threadIdx.x;
        const float inv_n = 1.0f / (float)ROWS;
        float mean = stats[l] * inv_n;
        float var  = stats[64 + l] * inv_n - mean * mean;
        float sc   = gamma[l] * rsqrtf(var + EPS);
        s[l] = sc;
        b[l] = beta[l] - mean * sc;
    }
    __syncthreads();

    f32x4* p = (f32x4*)y;
    const size_t ntot = (size_t)ROWS * CH / 4;
    size_t i = (size_t)blockIdx.x * blockDim.x + threadIdx.x;
    const size_t stride = (size_t)gridDim.x * blockDim.x;
    for (; i < ntot; i += stride) {
        f32x4 v = p[i];
        const int c0 = ((int)i & 15) * 4;
        v[0] = fmaf(v[0], s[c0],     b[c0]);
        v[1] = fmaf(v[1], s[c0 + 1], b[c0 + 1]);
        v[2] = fmaf(v[2], s[c0 + 2], b[c0 + 2]);
        v[3] = fmaf(v[3], s[c0 + 3], b[c0 + 3]);
        p[i] = v;
    }
}

extern "C" void kernel_launch(void* const* d_in, const int* in_sizes, int n_in,
                              void* d_out, int out_size, void* d_ws, size_t ws_size,
                              hipStream_t stream)
{
    const float* x     = (const float*)d_in[0];
    const int*   idx   = (const int*)d_in[1];
    const float* W     = (const float*)d_in[2];
    const float* gamma = (const float*)d_in[3];
    const float* beta  = (const float*)d_in[4];

    float*    y     = (float*)d_out;
    float*    stats = (float*)d_ws;                       // fallback only
    unsigned* wsb   = (unsigned*)(stats + 256);           // 8KB B-fragments
    char*     base  = (char*)d_ws + 16384;
    unsigned* xb16  = (unsigned*)base;                                   // 16.8MB
    float*    parts = (float*)(base + (size_t)ROWS * CH * 2);            // 1MB
    float*    part2 = parts + (size_t)NBLK * 128;                        // 8KB
    unsigned* yp    = (unsigned*)(part2 + (size_t)RBLK * 128);           // 16.8MB

    const size_t need = 16384 + (size_t)ROWS * CH * 2
                      + (size_t)NBLK * 128 * 4 + (size_t)RBLK * 128 * 4
                      + (size_t)ROWS * CH * 2;

    if (ws_size >= need) {
        k_cvt<<<dim3(2048), dim3(256), 0, stream>>>(x, xb16, W, wsb);
        k_fused_bf16<<<dim3(NBLK), dim3(256), 0, stream>>>(xb16, idx, wsb, yp, parts);
        k_reduce<<<dim3(RBLK), dim3(256), 0, stream>>>(parts, part2);
        k_norm_bf16<<<dim3(2048), dim3(256), 0, stream>>>(yp, y, part2, gamma, beta);
    } else {
        k_prep_fb<<<dim3(1), dim3(64), 0, stream>>>(W, wsb, stats);
        k_fused_f32<<<dim3(2048), dim3(256), 0, stream>>>(x, idx, wsb, y, stats);
        k_norm_f32<<<dim3(2048), dim3(256), 0, stream>>>(y, stats, gamma, beta);
    }
}

// Round 14
// 42.870 us; speedup vs baseline: 1.1378x; 1.0324x over previous
//
#include <hip/hip_runtime.h>

namespace {
constexpr int NPTS = 16384;
constexpr int CH   = 64;
constexpr int KNN  = 16;
constexpr int ROWS = 8 * NPTS;
constexpr float EPS = 1e-5f;
constexpr int NBLK = 1024;           // k_fused grid (128 rows/block, 2 tiles/wave)
constexpr int RBLK = 16;             // k_reduce grid
}

typedef __attribute__((ext_vector_type(8))) short  short8;
typedef __attribute__((ext_vector_type(4))) float  f32x4;
typedef __attribute__((ext_vector_type(4))) unsigned uint4v;
typedef __attribute__((ext_vector_type(2))) unsigned uint2v;
typedef __attribute__((ext_vector_type(4))) int    int4v;

static __device__ __forceinline__ unsigned pk_bf16(float lo, float hi) {
    unsigned r;
    asm("v_cvt_pk_bf16_f32 %0, %1, %2" : "=v"(r) : "v"(lo), "v"(hi));
    return r;
}

// Volatile packed 16-bit signed max (== relu(max) for bf16 with 0 seed).
#define PKM(D, A, B) asm volatile("v_pk_max_i16 %0, %1, %2" : "=v"(D) : "v"(A), "v"(B))

static __device__ __host__ __forceinline__ unsigned f2bf(float f) {
    unsigned u = __builtin_bit_cast(unsigned, f);
    return (u + 0x7fffu + ((u >> 16) & 1u)) >> 16;   // RNE
}

// W -> bf16 B-fragments (per-lane MFMA order).
static __device__ __forceinline__ void prep_wfrags(const float* __restrict__ W,
                                                   unsigned* __restrict__ wsb, int l)
{
    const int nq = l >> 4, nr = l & 15;
#pragma unroll
    for (int ct = 0; ct < 4; ++ct)
#pragma unroll
        for (int kh = 0; kh < 2; ++kh) {
            uint4v d;
#pragma unroll
            for (int dj = 0; dj < 4; ++dj) {
                const int k0 = kh * 32 + nq * 8 + dj * 2;
                unsigned lo = f2bf(W[(size_t)k0 * CH + ct * 16 + nr]);
                unsigned hi = f2bf(W[(size_t)(k0 + 1) * CH + ct * 16 + nr]);
                d[dj] = lo | (hi << 16);
            }
            ((uint4v*)wsb)[(ct * 2 + kh) * 64 + l] = d;
        }
}

// x (f32) -> bf16 rows of 128B, XCD-pinned (batch = blockIdx&7).
// CACHED loads (L3-resident across replays; NT costs 2-3us — r10/r12/r13).
__global__ __launch_bounds__(256)
void k_cvt(const float* __restrict__ x, unsigned* __restrict__ xb16,
           const float* __restrict__ W, unsigned* __restrict__ wsb)
{
    if (blockIdx.x == 0 && threadIdx.x < 64) prep_wfrags(W, wsb, threadIdx.x);
    const int batch = blockIdx.x & 7;
    const int chunk = blockIdx.x >> 3;
    const int lane8 = threadIdx.x & 7;
    const int rr    = threadIdx.x >> 3;
    const float*  xb = x    + (size_t)batch * NPTS * CH;
    unsigned*     ob = xb16 + (size_t)batch * NPTS * 32;
#pragma unroll
    for (int h = 0; h < 2; ++h) {
        const int row = chunk * 64 + h * 32 + rr;
        const f32x4* src = (const f32x4*)(xb + (size_t)row * CH + lane8 * 8);
        f32x4 v0 = src[0], v1 = src[1];
        uint4v d;
        d[0] = pk_bf16(v0[0], v0[1]);
        d[1] = pk_bf16(v0[2], v0[3]);
        d[2] = pk_bf16(v1[0], v1[1]);
        d[3] = pk_bf16(v1[2], v1[3]);
        *(uint4v*)(ob + (size_t)row * 32 + lane8 * 4) = d;
    }
}

// Main fused kernel: 2 tiles per wave, software-pipelined — tile1's 32 gathers
// are issued BEFORE tile0's MFMA+store, so t1 latency hides under t0 tail work.
__global__ __launch_bounds__(256)
void k_fused_bf16(const unsigned* __restrict__ xb16, const int* __restrict__ idx,
                  const unsigned* __restrict__ wsb, unsigned* __restrict__ yp,
                  float* __restrict__ partials)
{
    __shared__ __align__(16) ushort   Atile[4][16 * 64];  // per-wave, XOR-swizzled
    __shared__ __align__(16) int      Ibuf[4][256];       // per-wave 16x16 idx
    __shared__ __align__(16) unsigned Blds[2048];         // 8KB B-fragments
    __shared__ float bs1[64], bs2[64];

    const int lane  = threadIdx.x & 63;
    const int wave  = threadIdx.x >> 6;
    const int batch = blockIdx.x & 7;                     // XCD-aligned
    const int chunk = blockIdx.x >> 3;                    // 0..127

    ((uint4v*)Blds)[threadIdx.x]       = ((const uint4v*)wsb)[threadIdx.x];
    ((uint4v*)Blds)[threadIdx.x + 256] = ((const uint4v*)wsb)[threadIdx.x + 256];
    if (threadIdx.x < 64)       bs1[threadIdx.x] = 0.f;
    else if (threadIdx.x < 128) bs2[threadIdx.x - 64] = 0.f;
    __syncthreads();

    const unsigned* __restrict__ xb = xb16 + (size_t)batch * NPTS * 32;
    const int*      __restrict__ ib = idx  + (size_t)batch * NPTS * KNN;
    unsigned*       __restrict__ yb = yp   + (size_t)batch * NPTS * 32;

    const int r0 = chunk * 128 + wave * 16;               // tile0; tile1 = r0+64
    const int g8 = lane >> 3, c8 = lane & 7;
    const int c4 = lane & 15, qq = lane >> 4;
    const unsigned off16 = (unsigned)c8 * 16u;
    const int key = (c4 & 7) << 4;
    char* aw = (char*)&Atile[wave][0];

    short8 bfr[8];
#pragma unroll
    for (int f = 0; f < 8; ++f)
        bfr[f] = __builtin_bit_cast(short8, ((const uint4v*)Blds)[f * 64 + lane]);

    float sC1[4] = {0.f, 0.f, 0.f, 0.f};                  // per-CT stats partials
    float sC2[4] = {0.f, 0.f, 0.f, 0.f};

    // ---- tile0: idx stage + addresses
    int4v iq0 = ((const int4v*)(ib + (size_t)r0 * KNN))[lane];
    *(int4v*)&Ibuf[wave][lane * 4] = iq0;
    const int4v* Ip = (const int4v*)&Ibuf[wave][0];
    int ia[16], ibx[16];
    *(int4v*)&ia[0]  = Ip[g8 * 4 + 0];       *(int4v*)&ia[4]  = Ip[g8 * 4 + 1];
    *(int4v*)&ia[8]  = Ip[g8 * 4 + 2];       *(int4v*)&ia[12] = Ip[g8 * 4 + 3];
    *(int4v*)&ibx[0] = Ip[(g8 + 8) * 4 + 0]; *(int4v*)&ibx[4] = Ip[(g8 + 8) * 4 + 1];
    *(int4v*)&ibx[8] = Ip[(g8 + 8) * 4 + 2]; *(int4v*)&ibx[12]= Ip[(g8 + 8) * 4 + 3];

    uint4v va[16], vb[16];
#pragma unroll
    for (int j = 0; j < 16; ++j)
        asm volatile("global_load_dwordx4 %0, %1, %2"
                     : "=v"(va[j]) : "v"((unsigned)ia[j] * 128u + off16), "s"(xb));
#pragma unroll
    for (int j = 0; j < 16; ++j)
        asm volatile("global_load_dwordx4 %0, %1, %2"
                     : "=v"(vb[j]) : "v"((unsigned)ibx[j] * 128u + off16), "s"(xb));

    // tile1 idx load flies with tile0 gathers
    int4v iq1 = ((const int4v*)(ib + (size_t)(r0 + 64) * KNN))[lane];

    asm volatile("s_waitcnt vmcnt(0)" ::: "memory");
    __builtin_amdgcn_sched_barrier(0);

    uint4v accA = {0, 0, 0, 0}, accB = {0, 0, 0, 0};      // seed 0 == relu
#pragma unroll
    for (int j = 0; j < 16; ++j) {
        PKM(accA[0], accA[0], va[j][0]); PKM(accA[1], accA[1], va[j][1]);
        PKM(accA[2], accA[2], va[j][2]); PKM(accA[3], accA[3], va[j][3]);
    }
#pragma unroll
    for (int j = 0; j < 16; ++j) {
        PKM(accB[0], accB[0], vb[j][0]); PKM(accB[1], accB[1], vb[j][1]);
        PKM(accB[2], accB[2], vb[j][2]); PKM(accB[3], accB[3], vb[j][3]);
    }

    // ---- stage tile1 idx (same-wave DS ops are in-order: safe after Ip reads)
    *(int4v*)&Ibuf[wave][lane * 4] = iq1;
    *(int4v*)&ia[0]  = Ip[g8 * 4 + 0];       *(int4v*)&ia[4]  = Ip[g8 * 4 + 1];
    *(int4v*)&ia[8]  = Ip[g8 * 4 + 2];       *(int4v*)&ia[12] = Ip[g8 * 4 + 3];
    *(int4v*)&ibx[0] = Ip[(g8 + 8) * 4 + 0]; *(int4v*)&ibx[4] = Ip[(g8 + 8) * 4 + 1];
    *(int4v*)&ibx[8] = Ip[(g8 + 8) * 4 + 2]; *(int4v*)&ibx[12]= Ip[(g8 + 8) * 4 + 3];

    // issue tile1 gathers NOW (into t0-dead va/vb) — latency hides under t0 tail
#pragma unroll
    for (int j = 0; j < 16; ++j)
        asm volatile("global_load_dwordx4 %0, %1, %2"
                     : "=v"(va[j]) : "v"((unsigned)ia[j] * 128u + off16), "s"(xb));
#pragma unroll
    for (int j = 0; j < 16; ++j)
        asm volatile("global_load_dwordx4 %0, %1, %2"
                     : "=v"(vb[j]) : "v"((unsigned)ibx[j] * 128u + off16), "s"(xb));
    __builtin_amdgcn_sched_barrier(0);                    // keep t0 tail AFTER issue

    // ---- tile tail macro: Atile write -> frags -> MFMA -> yp store -> stats accum
#define TILE_TAIL(RBASE)                                                            \
    {                                                                               \
        *(uint4v*)(aw + ((g8 * 128 + c8 * 16) ^ (g8 << 4)))       = accA;           \
        *(uint4v*)(aw + (((g8 + 8) * 128 + c8 * 16) ^ (g8 << 4))) = accB;           \
        short8 a0 = *(const short8*)(aw + ((c4 * 128 + qq * 16) ^ key));            \
        short8 a1 = *(const short8*)(aw + ((c4 * 128 + 64 + qq * 16) ^ key));       \
        f32x4 acc0 = {0,0,0,0}, acc1 = {0,0,0,0}, acc2 = {0,0,0,0}, acc3 = {0,0,0,0}; \
        acc0 = __builtin_amdgcn_mfma_f32_16x16x32_bf16(a0, bfr[0], acc0, 0, 0, 0);  \
        acc0 = __builtin_amdgcn_mfma_f32_16x16x32_bf16(a1, bfr[1], acc0, 0, 0, 0);  \
        acc1 = __builtin_amdgcn_mfma_f32_16x16x32_bf16(a0, bfr[2], acc1, 0, 0, 0);  \
        acc1 = __builtin_amdgcn_mfma_f32_16x16x32_bf16(a1, bfr[3], acc1, 0, 0, 0);  \
        acc2 = __builtin_amdgcn_mfma_f32_16x16x32_bf16(a0, bfr[4], acc2, 0, 0, 0);  \
        acc2 = __builtin_amdgcn_mfma_f32_16x16x32_bf16(a1, bfr[5], acc2, 0, 0, 0);  \
        acc3 = __builtin_amdgcn_mfma_f32_16x16x32_bf16(a0, bfr[6], acc3, 0, 0, 0);  \
        acc3 = __builtin_amdgcn_mfma_f32_16x16x32_bf16(a1, bfr[7], acc3, 0, 0, 0);  \
        unsigned* ypr = yb + (size_t)((RBASE) + qq * 4) * 32 + c4 * 2;              \
        { uint2v pr; pr[0] = pk_bf16(acc0[0], acc1[0]);                             \
          pr[1] = pk_bf16(acc2[0], acc3[0]); *(uint2v*)(ypr + 0)  = pr; }           \
        { uint2v pr; pr[0] = pk_bf16(acc0[1], acc1[1]);                             \
          pr[1] = pk_bf16(acc2[1], acc3[1]); *(uint2v*)(ypr + 32) = pr; }           \
        { uint2v pr; pr[0] = pk_bf16(acc0[2], acc1[2]);                             \
          pr[1] = pk_bf16(acc2[2], acc3[2]); *(uint2v*)(ypr + 64) = pr; }           \
        { uint2v pr; pr[0] = pk_bf16(acc0[3], acc1[3]);                             \
          pr[1] = pk_bf16(acc2[3], acc3[3]); *(uint2v*)(ypr + 96) = pr; }           \
        sC1[0] += (acc0[0] + acc0[1]) + (acc0[2] + acc0[3]);                        \
        sC2[0] += (acc0[0]*acc0[0] + acc0[1]*acc0[1]) + (acc0[2]*acc0[2] + acc0[3]*acc0[3]); \
        sC1[1] += (acc1[0] + acc1[1]) + (acc1[2] + acc1[3]);                        \
        sC2[1] += (acc1[0]*acc1[0] + acc1[1]*acc1[1]) + (acc1[2]*acc1[2] + acc1[3]*acc1[3]); \
        sC1[2] += (acc2[0] + acc2[1]) + (acc2[2] + acc2[3]);                        \
        sC2[2] += (acc2[0]*acc2[0] + acc2[1]*acc2[1]) + (acc2[2]*acc2[2] + acc2[3]*acc2[3]); \
        sC1[3] += (acc3[0] + acc3[1]) + (acc3[2] + acc3[3]);                        \
        sC2[3] += (acc3[0]*acc3[0] + acc3[1]*acc3[1]) + (acc3[2]*acc3[2] + acc3[3]*acc3[3]); \
    }

    TILE_TAIL(r0)                                         // tile0 (t1 in flight)

    // drain tile1: allow the 4 t0 yp stores outstanding; all 32 loads retired
    asm volatile("s_waitcnt vmcnt(4)" ::: "memory");
    __builtin_amdgcn_sched_barrier(0);

    accA[0] = accA[1] = accA[2] = accA[3] = 0u;
    accB[0] = accB[1] = accB[2] = accB[3] = 0u;
#pragma unroll
    for (int j = 0; j < 16; ++j) {
        PKM(accA[0], accA[0], va[j][0]); PKM(accA[1], accA[1], va[j][1]);
        PKM(accA[2], accA[2], va[j][2]); PKM(accA[3], accA[3], va[j][3]);
    }
#pragma unroll
    for (int j = 0; j < 16; ++j) {
        PKM(accB[0], accB[0], vb[j][0]); PKM(accB[1], accB[1], vb[j][1]);
        PKM(accB[2], accB[2], vb[j][2]); PKM(accB[3], accB[3], vb[j][3]);
    }

    TILE_TAIL(r0 + 64)                                    // tile1
#undef TILE_TAIL

    // ---- stats: one shuffle+atomic pass covering both tiles
#pragma unroll
    for (int ct = 0; ct < 4; ++ct) {
        float s1 = sC1[ct], s2 = sC2[ct];
        s1 += __shfl_xor(s1, 16); s1 += __shfl_xor(s1, 32);
        s2 += __shfl_xor(s2, 16); s2 += __shfl_xor(s2, 32);
        if (lane < 16) {
            atomicAdd(&bs1[ct * 16 + lane], s1);
            atomicAdd(&bs2[ct * 16 + lane], s2);
        }
    }
    __syncthreads();
    if (threadIdx.x < 128)
        partials[(size_t)blockIdx.x * 128 + threadIdx.x] =
            (threadIdx.x < 64) ? bs1[threadIdx.x] : bs2[threadIdx.x - 64];
}

// partials[1024][128] -> partial2[16][128]
__global__ __launch_bounds__(256)
void k_reduce(const float* __restrict__ partials, float* __restrict__ partial2)
{
    const int t = threadIdx.x;
    const int c = t & 127, h = t >> 7;
    const float* p = partials + ((size_t)blockIdx.x * 64 + h * 32) * 128 + c;
    float s = 0.f;
#pragma unroll 8
    for (int r = 0; r < 32; ++r) s += p[(size_t)r * 128];
    __shared__ float red[256];
    red[t] = s;
    __syncthreads();
    if (t < 128) partial2[(size_t)blockIdx.x * 128 + t] = red[t] + red[t + 128];
}

// bf16-y normalize (unchanged from r13)
__global__ __launch_bounds__(256)
void k_norm_bf16(const unsigned* __restrict__ yp, float* __restrict__ y,
                 const float* __restrict__ partial2,
                 const float* __restrict__ gamma, const float* __restrict__ beta)
{
    __shared__ float s[CH], b[CH];
    if (threadIdx.x < CH) {
        const int l = threadIdx.x;
        float s1 = 0.f, s2 = 0.f;
#pragma unroll
        for (int k = 0; k < RBLK; ++k) {
            s1 += partial2[k * 128 + l];
            s2 += partial2[k * 128 + 64 + l];
        }
        const float inv_n = 1.0f / (float)ROWS;
        float mean = s1 * inv_n;
        float var  = s2 * inv_n - mean * mean;
        float sc   = gamma[l] * rsqrtf(var + EPS);
        s[l] = sc;
        b[l] = beta[l] - mean * sc;
    }
    __syncthreads();

    const size_t ntot = (size_t)ROWS * 16;
    size_t i = (size_t)blockIdx.x * blockDim.x + threadIdx.x;
    const size_t stride = (size_t)gridDim.x * blockDim.x;
    for (; i < ntot; i += stride) {
        const size_t row = i >> 4;
        const int c4 = (int)i & 15;
        uint2v p = *(const uint2v*)(yp + row * 32 + c4 * 2);
        float v0 = __uint_as_float(p[0] << 16);
        float v1 = __uint_as_float(p[0] & 0xffff0000u);
        float v2 = __uint_as_float(p[1] << 16);
        float v3 = __uint_as_float(p[1] & 0xffff0000u);
        float* yr = y + row * CH;
        yr[c4]      = fmaf(v0, s[c4],      b[c4]);
        yr[c4 + 16] = fmaf(v1, s[c4 + 16], b[c4 + 16]);
        yr[c4 + 32] = fmaf(v2, s[c4 + 32], b[c4 + 32]);
        yr[c4 + 48] = fmaf(v3, s[c4 + 48], b[c4 + 48]);
    }
}

// ---- fallback path (ws too small): round-2 f32 kernel + atomic stats ----
__global__ __launch_bounds__(64)
void k_prep_fb(const float* __restrict__ W, unsigned* __restrict__ wsb,
               float* __restrict__ stats)
{
    if (threadIdx.x < 64) {
        stats[threadIdx.x] = 0.f;
        stats[64 + threadIdx.x] = 0.f;
        prep_wfrags(W, wsb, threadIdx.x);
    }
}

__global__ __launch_bounds__(256)
void k_fused_f32(const float* __restrict__ x, const int* __restrict__ idx,
                 const unsigned* __restrict__ wsb, float* __restrict__ y,
                 float* __restrict__ stats)
{
    __shared__ __align__(16) ushort Atile[4][16 * 64];
    __shared__ __align__(16) int    Ibuf[4][256];
    __shared__ float bs1[64], bs2[64];

    const int lane  = threadIdx.x & 63;
    const int wave  = threadIdx.x >> 6;
    const int batch = blockIdx.x & 7;
    const int chunk = blockIdx.x >> 3;

    if (threadIdx.x < 64)       bs1[threadIdx.x] = 0.f;
    else if (threadIdx.x < 128) bs2[threadIdx.x - 64] = 0.f;
    __syncthreads();

    const int r0 = chunk * 64 + wave * 16;
    const float* __restrict__ xb = x   + (size_t)batch * NPTS * CH;
    const int*   __restrict__ ib = idx + (size_t)batch * NPTS * KNN;
    float*       __restrict__ yb = y   + (size_t)batch * NPTS * CH;

    const int c4 = lane & 15;
    const int qq = lane >> 4;

    int4v iq = ((const int4v*)(ib + (size_t)r0 * KNN))[lane];
    *(int4v*)&Ibuf[wave][lane * 4] = iq;

    short8 bfr[8];
#pragma unroll
    for (int f = 0; f < 8; ++f)
        bfr[f] = __builtin_bit_cast(short8, ((const uint4v*)wsb)[f * 64 + lane]);

    char* aw = (char*)&Atile[wave][0];
    const f32x4* xb4 = (const f32x4*)xb;

#pragma unroll
    for (int g = 0; g < 4; ++g) {
        const int row = 4 * g + qq;
        const int* ip = &Ibuf[wave][row * KNN];
        f32x4 acc = {0.f, 0.f, 0.f, 0.f};
#pragma unroll
        for (int j = 0; j < KNN; ++j) {
            const int n = ip[j];
            f32x4 v = xb4[n * 16 + c4];
            acc[0] = fmaxf(acc[0], v[0]);
            acc[1] = fmaxf(acc[1], v[1]);
            acc[2] = fmaxf(acc[2], v[2]);
            acc[3] = fmaxf(acc[3], v[3]);
        }
        uint2v pw;
        pw[0] = pk_bf16(acc[0], acc[1]);
        pw[1] = pk_bf16(acc[2], acc[3]);
        const int wb = ((row * 128) + c4 * 8) ^ ((row & 7) << 4);
        *(uint2v*)(aw + wb) = pw;
    }

    const int key = (c4 & 7) << 4;
    short8 a0 = *(const short8*)(aw + ((c4 * 128 + qq * 16) ^ key));
    short8 a1 = *(const short8*)(aw + ((c4 * 128 + 64 + qq * 16) ^ key));

    f32x4 acc0 = {0,0,0,0}, acc1 = {0,0,0,0}, acc2 = {0,0,0,0}, acc3 = {0,0,0,0};
    acc0 = __builtin_amdgcn_mfma_f32_16x16x32_bf16(a0, bfr[0], acc0, 0, 0, 0);
    acc0 = __builtin_amdgcn_mfma_f32_16x16x32_bf16(a1, bfr[1], acc0, 0, 0, 0);
    acc1 = __builtin_amdgcn_mfma_f32_16x16x32_bf16(a0, bfr[2], acc1, 0, 0, 0);
    acc1 = __builtin_amdgcn_mfma_f32_16x16x32_bf16(a1, bfr[3], acc1, 0, 0, 0);
    acc2 = __builtin_amdgcn_mfma_f32_16x16x32_bf16(a0, bfr[4], acc2, 0, 0, 0);
    acc2 = __builtin_amdgcn_mfma_f32_16x16x32_bf16(a1, bfr[5], acc2, 0, 0, 0);
    acc3 = __builtin_amdgcn_mfma_f32_16x16x32_bf16(a0, bfr[6], acc3, 0, 0, 0);
    acc3 = __builtin_amdgcn_mfma_f32_16x16x32_bf16(a1, bfr[7], acc3, 0, 0, 0);

    float* yrow = yb + (size_t)(r0 + qq * 4) * CH + c4;
#define DO_CT(CT, ACC)                                                              \
    {                                                                               \
        yrow[0 * CH + CT * 16] = ACC[0];                                            \
        yrow[1 * CH + CT * 16] = ACC[1];                                            \
        yrow[2 * CH + CT * 16] = ACC[2];                                            \
        yrow[3 * CH + CT * 16] = ACC[3];                                            \
        float s1 = (ACC[0] + ACC[1]) + (ACC[2] + ACC[3]);                           \
        float s2 = (ACC[0]*ACC[0] + ACC[1]*ACC[1]) + (ACC[2]*ACC[2] + ACC[3]*ACC[3]); \
        s1 += __shfl_xor(s1, 16); s1 += __shfl_xor(s1, 32);                         \
        s2 += __shfl_xor(s2, 16); s2 += __shfl_xor(s2, 32);                         \
        if (lane < 16) {                                                            \
            atomicAdd(&bs1[CT * 16 + lane], s1);                                    \
            atomicAdd(&bs2[CT * 16 + lane], s2);                                    \
        }                                                                           \
    }
    DO_CT(0, acc0) DO_CT(1, acc1) DO_CT(2, acc2) DO_CT(3, acc3)
#undef DO_CT

    __syncthreads();
    if (threadIdx.x < 64)        atomicAdd(&stats[threadIdx.x], bs1[threadIdx.x]);
    else if (threadIdx.x < 128)  atomicAdd(&stats[threadIdx.x], bs2[threadIdx.x - 64]);
}

// fallback normalize: in-place on f32 y, stats[128] source
__global__ __launch_bounds__(256)
void k_norm_f32(float* __restrict__ y, const float* __restrict__ stats,
                const float* __restrict__ gamma, const float* __restrict__ beta)
{
    __shared__ float s[CH], b[CH];
    if (threadIdx.x < CH) {
        const int l = threadIdx.x;
        const float inv_n = 1.0f / (float)ROWS;
        float mean = stats[l] * inv_n;
        float var  = stats[64 + l] * inv_n - mean * mean;
        float sc   = gamma[l] * rsqrtf(var + EPS);
        s[l] = sc;
        b[l] = beta[l] - mean * sc;
    }
    __syncthreads();

    f32x4* p = (f32x4*)y;
    const size_t ntot = (size_t)ROWS * CH / 4;
    size_t i = (size_t)blockIdx.x * blockDim.x + threadIdx.x;
    const size_t stride = (size_t)gridDim.x * blockDim.x;
    for (; i < ntot; i += stride) {
        f32x4 v = p[i];
        const int c0 = ((int)i & 15) * 4;
        v[0] = fmaf(v[0], s[c0],     b[c0]);
        v[1] = fmaf(v[1], s[c0 + 1], b[c0 + 1]);
        v[2] = fmaf(v[2], s[c0 + 2], b[c0 + 2]);
        v[3] = fmaf(v[3], s[c0 + 3], b[c0 + 3]);
        p[i] = v;
    }
}

extern "C" void kernel_launch(void* const* d_in, const int* in_sizes, int n_in,
                              void* d_out, int out_size, void* d_ws, size_t ws_size,
                              hipStream_t stream)
{
    const float* x     = (const float*)d_in[0];
    const int*   idx   = (const int*)d_in[1];
    const float* W     = (const float*)d_in[2];
    const float* gamma = (const float*)d_in[3];
    const float* beta  = (const float*)d_in[4];

    float*    y     = (float*)d_out;
    float*    stats = (float*)d_ws;                       // fallback only
    unsigned* wsb   = (unsigned*)(stats + 256);           // 8KB B-fragments
    char*     base  = (char*)d_ws + 16384;
    unsigned* xb16  = (unsigned*)base;                                   // 16.8MB
    float*    parts = (float*)(base + (size_t)ROWS * CH * 2);            // 512KB
    float*    part2 = parts + (size_t)NBLK * 128;                        // 8KB
    unsigned* yp    = (unsigned*)(part2 + (size_t)RBLK * 128);           // 16.8MB

    const size_t need = 16384 + (size_t)ROWS * CH * 2
                      + (size_t)NBLK * 128 * 4 + (size_t)RBLK * 128 * 4
                      + (size_t)ROWS * CH * 2;

    if (ws_size >= need) {
        k_cvt<<<dim3(2048), dim3(256), 0, stream>>>(x, xb16, W, wsb);
        k_fused_bf16<<<dim3(NBLK), dim3(256), 0, stream>>>(xb16, idx, wsb, yp, parts);
        k_reduce<<<dim3(RBLK), dim3(256), 0, stream>>>(parts, part2);
        k_norm_bf16<<<dim3(2048), dim3(256), 0, stream>>>(yp, y, part2, gamma, beta);
    } else {
        k_prep_fb<<<dim3(1), dim3(64), 0, stream>>>(W, wsb, stats);
        k_fused_f32<<<dim3(2048), dim3(256), 0, stream>>>(x, idx, wsb, y, stats);
        k_norm_f32<<<dim3(2048), dim3(256), 0, stream>>>(y, stats, gamma, beta);
    }
}

// Round 15
// 41.215 us; speedup vs baseline: 1.1835x; 1.0402x over previous
//
#include <hip/hip_runtime.h>

namespace {
constexpr int NPTS = 16384;
constexpr int CH   = 64;
constexpr int KNN  = 16;
constexpr int ROWS = 8 * NPTS;
constexpr float EPS = 1e-5f;
constexpr int NBLK = 1024;           // k_fused grid (128 rows/block, 2 tiles/wave)
constexpr int NBUCK = 16;            // stats buckets (64 contenders/address)
}

typedef __attribute__((ext_vector_type(8))) short  short8;
typedef __attribute__((ext_vector_type(4))) float  f32x4;
typedef __attribute__((ext_vector_type(4))) unsigned uint4v;
typedef __attribute__((ext_vector_type(2))) unsigned uint2v;
typedef __attribute__((ext_vector_type(4))) int    int4v;

static __device__ __forceinline__ unsigned pk_bf16(float lo, float hi) {
    unsigned r;
    asm("v_cvt_pk_bf16_f32 %0, %1, %2" : "=v"(r) : "v"(lo), "v"(hi));
    return r;
}

// Volatile packed 16-bit signed max (== relu(max) for bf16 with 0 seed).
#define PKM(D, A, B) asm volatile("v_pk_max_i16 %0, %1, %2" : "=v"(D) : "v"(A), "v"(B))

static __device__ __host__ __forceinline__ unsigned f2bf(float f) {
    unsigned u = __builtin_bit_cast(unsigned, f);
    return (u + 0x7fffu + ((u >> 16) & 1u)) >> 16;   // RNE
}

// W -> bf16 B-fragments (per-lane MFMA order).
static __device__ __forceinline__ void prep_wfrags(const float* __restrict__ W,
                                                   unsigned* __restrict__ wsb, int l)
{
    const int nq = l >> 4, nr = l & 15;
#pragma unroll
    for (int ct = 0; ct < 4; ++ct)
#pragma unroll
        for (int kh = 0; kh < 2; ++kh) {
            uint4v d;
#pragma unroll
            for (int dj = 0; dj < 4; ++dj) {
                const int k0 = kh * 32 + nq * 8 + dj * 2;
                unsigned lo = f2bf(W[(size_t)k0 * CH + ct * 16 + nr]);
                unsigned hi = f2bf(W[(size_t)(k0 + 1) * CH + ct * 16 + nr]);
                d[dj] = lo | (hi << 16);
            }
            ((uint4v*)wsb)[(ct * 2 + kh) * 64 + l] = d;
        }
}

// x (f32) -> bf16 rows of 128B, XCD-pinned (batch = blockIdx&7).
// CACHED loads (L3-resident across replays; NT costs 2-3us — r10/r12/r13).
// Block 0 also zeroes the 16 stats buckets and builds W fragments.
__global__ __launch_bounds__(256)
void k_cvt(const float* __restrict__ x, unsigned* __restrict__ xb16,
           const float* __restrict__ W, unsigned* __restrict__ wsb,
           float* __restrict__ stats16)
{
    if (blockIdx.x == 0) {
        if (threadIdx.x < 64) prep_wfrags(W, wsb, threadIdx.x);
        for (int i = threadIdx.x; i < NBUCK * 128; i += 256) stats16[i] = 0.f;
    }
    const int batch = blockIdx.x & 7;
    const int chunk = blockIdx.x >> 3;
    const int lane8 = threadIdx.x & 7;
    const int rr    = threadIdx.x >> 3;
    const float*  xb = x    + (size_t)batch * NPTS * CH;
    unsigned*     ob = xb16 + (size_t)batch * NPTS * 32;
#pragma unroll
    for (int h = 0; h < 2; ++h) {
        const int row = chunk * 64 + h * 32 + rr;
        const f32x4* src = (const f32x4*)(xb + (size_t)row * CH + lane8 * 8);
        f32x4 v0 = src[0], v1 = src[1];
        uint4v d;
        d[0] = pk_bf16(v0[0], v0[1]);
        d[1] = pk_bf16(v0[2], v0[3]);
        d[2] = pk_bf16(v1[0], v1[1]);
        d[3] = pk_bf16(v1[2], v1[3]);
        *(uint4v*)(ob + (size_t)row * 32 + lane8 * 4) = d;
    }
}

// Main fused kernel: 2 tiles per wave, software-pipelined (r14 structure).
// Epilogue: one global atomicAdd per thread into bucket bid&15 (64-way
// contention, ~1us tail) — replaces the partials buffer + k_reduce dispatch.
__global__ __launch_bounds__(256)
void k_fused_bf16(const unsigned* __restrict__ xb16, const int* __restrict__ idx,
                  const unsigned* __restrict__ wsb, unsigned* __restrict__ yp,
                  float* __restrict__ stats16)
{
    __shared__ __align__(16) ushort   Atile[4][16 * 64];  // per-wave, XOR-swizzled
    __shared__ __align__(16) int      Ibuf[4][256];       // per-wave 16x16 idx
    __shared__ __align__(16) unsigned Blds[2048];         // 8KB B-fragments
    __shared__ float bs1[64], bs2[64];

    const int lane  = threadIdx.x & 63;
    const int wave  = threadIdx.x >> 6;
    const int batch = blockIdx.x & 7;                     // XCD-aligned
    const int chunk = blockIdx.x >> 3;                    // 0..127

    ((uint4v*)Blds)[threadIdx.x]       = ((const uint4v*)wsb)[threadIdx.x];
    ((uint4v*)Blds)[threadIdx.x + 256] = ((const uint4v*)wsb)[threadIdx.x + 256];
    if (threadIdx.x < 64)       bs1[threadIdx.x] = 0.f;
    else if (threadIdx.x < 128) bs2[threadIdx.x - 64] = 0.f;
    __syncthreads();

    const unsigned* __restrict__ xb = xb16 + (size_t)batch * NPTS * 32;
    const int*      __restrict__ ib = idx  + (size_t)batch * NPTS * KNN;
    unsigned*       __restrict__ yb = yp   + (size_t)batch * NPTS * 32;

    const int r0 = chunk * 128 + wave * 16;               // tile0; tile1 = r0+64
    const int g8 = lane >> 3, c8 = lane & 7;
    const int c4 = lane & 15, qq = lane >> 4;
    const unsigned off16 = (unsigned)c8 * 16u;
    const int key = (c4 & 7) << 4;
    char* aw = (char*)&Atile[wave][0];

    short8 bfr[8];
#pragma unroll
    for (int f = 0; f < 8; ++f)
        bfr[f] = __builtin_bit_cast(short8, ((const uint4v*)Blds)[f * 64 + lane]);

    float sC1[4] = {0.f, 0.f, 0.f, 0.f};                  // per-CT stats partials
    float sC2[4] = {0.f, 0.f, 0.f, 0.f};

    // ---- tile0: idx stage + addresses
    int4v iq0 = ((const int4v*)(ib + (size_t)r0 * KNN))[lane];
    *(int4v*)&Ibuf[wave][lane * 4] = iq0;
    const int4v* Ip = (const int4v*)&Ibuf[wave][0];
    int ia[16], ibx[16];
    *(int4v*)&ia[0]  = Ip[g8 * 4 + 0];       *(int4v*)&ia[4]  = Ip[g8 * 4 + 1];
    *(int4v*)&ia[8]  = Ip[g8 * 4 + 2];       *(int4v*)&ia[12] = Ip[g8 * 4 + 3];
    *(int4v*)&ibx[0] = Ip[(g8 + 8) * 4 + 0]; *(int4v*)&ibx[4] = Ip[(g8 + 8) * 4 + 1];
    *(int4v*)&ibx[8] = Ip[(g8 + 8) * 4 + 2]; *(int4v*)&ibx[12]= Ip[(g8 + 8) * 4 + 3];

    uint4v va[16], vb[16];
#pragma unroll
    for (int j = 0; j < 16; ++j)
        asm volatile("global_load_dwordx4 %0, %1, %2"
                     : "=v"(va[j]) : "v"((unsigned)ia[j] * 128u + off16), "s"(xb));
#pragma unroll
    for (int j = 0; j < 16; ++j)
        asm volatile("global_load_dwordx4 %0, %1, %2"
                     : "=v"(vb[j]) : "v"((unsigned)ibx[j] * 128u + off16), "s"(xb));

    // tile1 idx load flies with tile0 gathers
    int4v iq1 = ((const int4v*)(ib + (size_t)(r0 + 64) * KNN))[lane];

    asm volatile("s_waitcnt vmcnt(0)" ::: "memory");
    __builtin_amdgcn_sched_barrier(0);

    uint4v accA = {0, 0, 0, 0}, accB = {0, 0, 0, 0};      // seed 0 == relu
#pragma unroll
    for (int j = 0; j < 16; ++j) {
        PKM(accA[0], accA[0], va[j][0]); PKM(accA[1], accA[1], va[j][1]);
        PKM(accA[2], accA[2], va[j][2]); PKM(accA[3], accA[3], va[j][3]);
    }
#pragma unroll
    for (int j = 0; j < 16; ++j) {
        PKM(accB[0], accB[0], vb[j][0]); PKM(accB[1], accB[1], vb[j][1]);
        PKM(accB[2], accB[2], vb[j][2]); PKM(accB[3], accB[3], vb[j][3]);
    }

    // ---- stage tile1 idx (same-wave DS ops are in-order: safe after Ip reads)
    *(int4v*)&Ibuf[wave][lane * 4] = iq1;
    *(int4v*)&ia[0]  = Ip[g8 * 4 + 0];       *(int4v*)&ia[4]  = Ip[g8 * 4 + 1];
    *(int4v*)&ia[8]  = Ip[g8 * 4 + 2];       *(int4v*)&ia[12] = Ip[g8 * 4 + 3];
    *(int4v*)&ibx[0] = Ip[(g8 + 8) * 4 + 0]; *(int4v*)&ibx[4] = Ip[(g8 + 8) * 4 + 1];
    *(int4v*)&ibx[8] = Ip[(g8 + 8) * 4 + 2]; *(int4v*)&ibx[12]= Ip[(g8 + 8) * 4 + 3];

    // issue tile1 gathers NOW (into t0-dead va/vb) — latency hides under t0 tail
#pragma unroll
    for (int j = 0; j < 16; ++j)
        asm volatile("global_load_dwordx4 %0, %1, %2"
                     : "=v"(va[j]) : "v"((unsigned)ia[j] * 128u + off16), "s"(xb));
#pragma unroll
    for (int j = 0; j < 16; ++j)
        asm volatile("global_load_dwordx4 %0, %1, %2"
                     : "=v"(vb[j]) : "v"((unsigned)ibx[j] * 128u + off16), "s"(xb));
    __builtin_amdgcn_sched_barrier(0);                    // keep t0 tail AFTER issue

    // ---- tile tail macro: Atile write -> frags -> MFMA -> yp store -> stats accum
#define TILE_TAIL(RBASE)                                                            \
    {                                                                               \
        *(uint4v*)(aw + ((g8 * 128 + c8 * 16) ^ (g8 << 4)))       = accA;           \
        *(uint4v*)(aw + (((g8 + 8) * 128 + c8 * 16) ^ (g8 << 4))) = accB;           \
        short8 a0 = *(const short8*)(aw + ((c4 * 128 + qq * 16) ^ key));            \
        short8 a1 = *(const short8*)(aw + ((c4 * 128 + 64 + qq * 16) ^ key));       \
        f32x4 acc0 = {0,0,0,0}, acc1 = {0,0,0,0}, acc2 = {0,0,0,0}, acc3 = {0,0,0,0}; \
        acc0 = __builtin_amdgcn_mfma_f32_16x16x32_bf16(a0, bfr[0], acc0, 0, 0, 0);  \
        acc0 = __builtin_amdgcn_mfma_f32_16x16x32_bf16(a1, bfr[1], acc0, 0, 0, 0);  \
        acc1 = __builtin_amdgcn_mfma_f32_16x16x32_bf16(a0, bfr[2], acc1, 0, 0, 0);  \
        acc1 = __builtin_amdgcn_mfma_f32_16x16x32_bf16(a1, bfr[3], acc1, 0, 0, 0);  \
        acc2 = __builtin_amdgcn_mfma_f32_16x16x32_bf16(a0, bfr[4], acc2, 0, 0, 0);  \
        acc2 = __builtin_amdgcn_mfma_f32_16x16x32_bf16(a1, bfr[5], acc2, 0, 0, 0);  \
        acc3 = __builtin_amdgcn_mfma_f32_16x16x32_bf16(a0, bfr[6], acc3, 0, 0, 0);  \
        acc3 = __builtin_amdgcn_mfma_f32_16x16x32_bf16(a1, bfr[7], acc3, 0, 0, 0);  \
        unsigned* ypr = yb + (size_t)((RBASE) + qq * 4) * 32 + c4 * 2;              \
        { uint2v pr; pr[0] = pk_bf16(acc0[0], acc1[0]);                             \
          pr[1] = pk_bf16(acc2[0], acc3[0]); *(uint2v*)(ypr + 0)  = pr; }           \
        { uint2v pr; pr[0] = pk_bf16(acc0[1], acc1[1]);                             \
          pr[1] = pk_bf16(acc2[1], acc3[1]); *(uint2v*)(ypr + 32) = pr; }           \
        { uint2v pr; pr[0] = pk_bf16(acc0[2], acc1[2]);                             \
          pr[1] = pk_bf16(acc2[2], acc3[2]); *(uint2v*)(ypr + 64) = pr; }           \
        { uint2v pr; pr[0] = pk_bf16(acc0[3], acc1[3]);                             \
          pr[1] = pk_bf16(acc2[3], acc3[3]); *(uint2v*)(ypr + 96) = pr; }           \
        sC1[0] += (acc0[0] + acc0[1]) + (acc0[2] + acc0[3]);                        \
        sC2[0] += (acc0[0]*acc0[0] + acc0[1]*acc0[1]) + (acc0[2]*acc0[2] + acc0[3]*acc0[3]); \
        sC1[1] += (acc1[0] + acc1[1]) + (acc1[2] + acc1[3]);                        \
        sC2[1] += (acc1[0]*acc1[0] + acc1[1]*acc1[1]) + (acc1[2]*acc1[2] + acc1[3]*acc1[3]); \
        sC1[2] += (acc2[0] + acc2[1]) + (acc2[2] + acc2[3]);                        \
        sC2[2] += (acc2[0]*acc2[0] + acc2[1]*acc2[1]) + (acc2[2]*acc2[2] + acc2[3]*acc2[3]); \
        sC1[3] += (acc3[0] + acc3[1]) + (acc3[2] + acc3[3]);                        \
        sC2[3] += (acc3[0]*acc3[0] + acc3[1]*acc3[1]) + (acc3[2]*acc3[2] + acc3[3]*acc3[3]); \
    }

    TILE_TAIL(r0)                                         // tile0 (t1 in flight)

    // drain tile1: allow the 4 t0 yp stores outstanding; all 32 loads retired
    asm volatile("s_waitcnt vmcnt(4)" ::: "memory");
    __builtin_amdgcn_sched_barrier(0);

    accA[0] = accA[1] = accA[2] = accA[3] = 0u;
    accB[0] = accB[1] = accB[2] = accB[3] = 0u;
#pragma unroll
    for (int j = 0; j < 16; ++j) {
        PKM(accA[0], accA[0], va[j][0]); PKM(accA[1], accA[1], va[j][1]);
        PKM(accA[2], accA[2], va[j][2]); PKM(accA[3], accA[3], va[j][3]);
    }
#pragma unroll
    for (int j = 0; j < 16; ++j) {
        PKM(accB[0], accB[0], vb[j][0]); PKM(accB[1], accB[1], vb[j][1]);
        PKM(accB[2], accB[2], vb[j][2]); PKM(accB[3], accB[3], vb[j][3]);
    }

    TILE_TAIL(r0 + 64)                                    // tile1
#undef TILE_TAIL

    // ---- stats: shuffle -> block LDS -> one global atomic per thread (bucketed)
#pragma unroll
    for (int ct = 0; ct < 4; ++ct) {
        float s1 = sC1[ct], s2 = sC2[ct];
        s1 += __shfl_xor(s1, 16); s1 += __shfl_xor(s1, 32);
        s2 += __shfl_xor(s2, 16); s2 += __shfl_xor(s2, 32);
        if (lane < 16) {
            atomicAdd(&bs1[ct * 16 + lane], s1);
            atomicAdd(&bs2[ct * 16 + lane], s2);
        }
    }
    __syncthreads();
    if (threadIdx.x < 128)
        atomicAdd(&stats16[(blockIdx.x & (NBUCK - 1)) * 128 + threadIdx.x],
                  (threadIdx.x < 64) ? bs1[threadIdx.x] : bs2[threadIdx.x - 64]);
}

// bf16-y normalize; folds the 16 stats buckets (8KB) in the header.
__global__ __launch_bounds__(256)
void k_norm_bf16(const unsigned* __restrict__ yp, float* __restrict__ y,
                 const float* __restrict__ stats16,
                 const float* __restrict__ gamma, const float* __restrict__ beta)
{
    __shared__ float s[CH], b[CH];
    if (threadIdx.x < CH) {
        const int l = threadIdx.x;
        float s1 = 0.f, s2 = 0.f;
#pragma unroll
        for (int k = 0; k < NBUCK; ++k) {
            s1 += stats16[k * 128 + l];
            s2 += stats16[k * 128 + 64 + l];
        }
        const float inv_n = 1.0f / (float)ROWS;
        float mean = s1 * inv_n;
        float var  = s2 * inv_n - mean * mean;
        float sc   = gamma[l] * rsqrtf(var + EPS);
        s[l] = sc;
        b[l] = beta[l] - mean * sc;
    }
    __syncthreads();

    const size_t ntot = (size_t)ROWS * 16;
    size_t i = (size_t)blockIdx.x * blockDim.x + threadIdx.x;
    const size_t stride = (size_t)gridDim.x * blockDim.x;
    for (; i < ntot; i += stride) {
        const size_t row = i >> 4;
        const int c4 = (int)i & 15;
        uint2v p = *(const uint2v*)(yp + row * 32 + c4 * 2);
        float v0 = __uint_as_float(p[0] << 16);
        float v1 = __uint_as_float(p[0] & 0xffff0000u);
        float v2 = __uint_as_float(p[1] << 16);
        float v3 = __uint_as_float(p[1] & 0xffff0000u);
        float* yr = y + row * CH;
        yr[c4]      = fmaf(v0, s[c4],      b[c4]);
        yr[c4 + 16] = fmaf(v1, s[c4 + 16], b[c4 + 16]);
        yr[c4 + 32] = fmaf(v2, s[c4 + 32], b[c4 + 32]);
        yr[c4 + 48] = fmaf(v3, s[c4 + 48], b[c4 + 48]);
    }
}

// ---- fallback path (ws too small): round-2 f32 kernel + atomic stats ----
__global__ __launch_bounds__(64)
void k_prep_fb(const float* __restrict__ W, unsigned* __restrict__ wsb,
               float* __restrict__ stats)
{
    if (threadIdx.x < 64) {
        stats[threadIdx.x] = 0.f;
        stats[64 + threadIdx.x] = 0.f;
        prep_wfrags(W, wsb, threadIdx.x);
    }
}

__global__ __launch_bounds__(256)
void k_fused_f32(const float* __restrict__ x, const int* __restrict__ idx,
                 const unsigned* __restrict__ wsb, float* __restrict__ y,
                 float* __restrict__ stats)
{
    __shared__ __align__(16) ushort Atile[4][16 * 64];
    __shared__ __align__(16) int    Ibuf[4][256];
    __shared__ float bs1[64], bs2[64];

    const int lane  = threadIdx.x & 63;
    const int wave  = threadIdx.x >> 6;
    const int batch = blockIdx.x & 7;
    const int chunk = blockIdx.x >> 3;

    if (threadIdx.x < 64)       bs1[threadIdx.x] = 0.f;
    else if (threadIdx.x < 128) bs2[threadIdx.x - 64] = 0.f;
    __syncthreads();

    const int r0 = chunk * 64 + wave * 16;
    const float* __restrict__ xb = x   + (size_t)batch * NPTS * CH;
    const int*   __restrict__ ib = idx + (size_t)batch * NPTS * KNN;
    float*       __restrict__ yb = y   + (size_t)batch * NPTS * CH;

    const int c4 = lane & 15;
    const int qq = lane >> 4;

    int4v iq = ((const int4v*)(ib + (size_t)r0 * KNN))[lane];
    *(int4v*)&Ibuf[wave][lane * 4] = iq;

    short8 bfr[8];
#pragma unroll
    for (int f = 0; f < 8; ++f)
        bfr[f] = __builtin_bit_cast(short8, ((const uint4v*)wsb)[f * 64 + lane]);

    char* aw = (char*)&Atile[wave][0];
    const f32x4* xb4 = (const f32x4*)xb;

#pragma unroll
    for (int g = 0; g < 4; ++g) {
        const int row = 4 * g + qq;
        const int* ip = &Ibuf[wave][row * KNN];
        f32x4 acc = {0.f, 0.f, 0.f, 0.f};
#pragma unroll
        for (int j = 0; j < KNN; ++j) {
            const int n = ip[j];
            f32x4 v = xb4[n * 16 + c4];
            acc[0] = fmaxf(acc[0], v[0]);
            acc[1] = fmaxf(acc[1], v[1]);
            acc[2] = fmaxf(acc[2], v[2]);
            acc[3] = fmaxf(acc[3], v[3]);
        }
        uint2v pw;
        pw[0] = pk_bf16(acc[0], acc[1]);
        pw[1] = pk_bf16(acc[2], acc[3]);
        const int wb = ((row * 128) + c4 * 8) ^ ((row & 7) << 4);
        *(uint2v*)(aw + wb) = pw;
    }

    const int key = (c4 & 7) << 4;
    short8 a0 = *(const short8*)(aw + ((c4 * 128 + qq * 16) ^ key));
    short8 a1 = *(const short8*)(aw + ((c4 * 128 + 64 + qq * 16) ^ key));

    f32x4 acc0 = {0,0,0,0}, acc1 = {0,0,0,0}, acc2 = {0,0,0,0}, acc3 = {0,0,0,0};
    acc0 = __builtin_amdgcn_mfma_f32_16x16x32_bf16(a0, bfr[0], acc0, 0, 0, 0);
    acc0 = __builtin_amdgcn_mfma_f32_16x16x32_bf16(a1, bfr[1], acc0, 0, 0, 0);
    acc1 = __builtin_amdgcn_mfma_f32_16x16x32_bf16(a0, bfr[2], acc1, 0, 0, 0);
    acc1 = __builtin_amdgcn_mfma_f32_16x16x32_bf16(a1, bfr[3], acc1, 0, 0, 0);
    acc2 = __builtin_amdgcn_mfma_f32_16x16x32_bf16(a0, bfr[4], acc2, 0, 0, 0);
    acc2 = __builtin_amdgcn_mfma_f32_16x16x32_bf16(a1, bfr[5], acc2, 0, 0, 0);
    acc3 = __builtin_amdgcn_mfma_f32_16x16x32_bf16(a0, bfr[6], acc3, 0, 0, 0);
    acc3 = __builtin_amdgcn_mfma_f32_16x16x32_bf16(a1, bfr[7], acc3, 0, 0, 0);

    float* yrow = yb + (size_t)(r0 + qq * 4) * CH + c4;
#define DO_CT(CT, ACC)                                                              \
    {                                                                               \
        yrow[0 * CH + CT * 16] = ACC[0];                                            \
        yrow[1 * CH + CT * 16] = ACC[1];                                            \
        yrow[2 * CH + CT * 16] = ACC[2];                                            \
        yrow[3 * CH + CT * 16] = ACC[3];                                            \
        float s1 = (ACC[0] + ACC[1]) + (ACC[2] + ACC[3]);                           \
        float s2 = (ACC[0]*ACC[0] + ACC[1]*ACC[1]) + (ACC[2]*ACC[2] + ACC[3]*ACC[3]); \
        s1 += __shfl_xor(s1, 16); s1 += __shfl_xor(s1, 32);                         \
        s2 += __shfl_xor(s2, 16); s2 += __shfl_xor(s2, 32);                         \
        if (lane < 16) {                                                            \
            atomicAdd(&bs1[CT * 16 + lane], s1);                                    \
            atomicAdd(&bs2[CT * 16 + lane], s2);                                    \
        }                                                                           \
    }
    DO_CT(0, acc0) DO_CT(1, acc1) DO_CT(2, acc2) DO_CT(3, acc3)
#undef DO_CT

    __syncthreads();
    if (threadIdx.x < 64)        atomicAdd(&stats[threadIdx.x], bs1[threadIdx.x]);
    else if (threadIdx.x < 128)  atomicAdd(&stats[threadIdx.x], bs2[threadIdx.x - 64]);
}

// fallback normalize: in-place on f32 y, stats[128] source
__global__ __launch_bounds__(256)
void k_norm_f32(float* __restrict__ y, const float* __restrict__ stats,
                const float* __restrict__ gamma, const float* __restrict__ beta)
{
    __shared__ float s[CH], b[CH];
    if (threadIdx.x < CH) {
        const int l = threadIdx.x;
        const float inv_n = 1.0f / (float)ROWS;
        float mean = stats[l] * inv_n;
        float var  = stats[64 + l] * inv_n - mean * mean;
        float sc   = gamma[l] * rsqrtf(var + EPS);
        s[l] = sc;
        b[l] = beta[l] - mean * sc;
    }
    __syncthreads();

    f32x4* p = (f32x4*)y;
    const size_t ntot = (size_t)ROWS * CH / 4;
    size_t i = (size_t)blockIdx.x * blockDim.x + threadIdx.x;
    const size_t stride = (size_t)gridDim.x * blockDim.x;
    for (; i < ntot; i += stride) {
        f32x4 v = p[i];
        const int c0 = ((int)i & 15) * 4;
        v[0] = fmaf(v[0], s[c0],     b[c0]);
        v[1] = fmaf(v[1], s[c0 + 1], b[c0 + 1]);
        v[2] = fmaf(v[2], s[c0 + 2], b[c0 + 2]);
        v[3] = fmaf(v[3], s[c0 + 3], b[c0 + 3]);
        p[i] = v;
    }
}

extern "C" void kernel_launch(void* const* d_in, const int* in_sizes, int n_in,
                              void* d_out, int out_size, void* d_ws, size_t ws_size,
                              hipStream_t stream)
{
    const float* x     = (const float*)d_in[0];
    const int*   idx   = (const int*)d_in[1];
    const float* W     = (const float*)d_in[2];
    const float* gamma = (const float*)d_in[3];
    const float* beta  = (const float*)d_in[4];

    float*    y       = (float*)d_out;
    float*    stats   = (float*)d_ws;                     // fallback only
    unsigned* wsb     = (unsigned*)(stats + 256);         // 8KB B-fragments
    char*     base    = (char*)d_ws + 16384;
    unsigned* xb16    = (unsigned*)base;                                 // 16.8MB
    float*    stats16 = (float*)(base + (size_t)ROWS * CH * 2);          // 8KB
    unsigned* yp      = (unsigned*)(stats16 + NBUCK * 128);              // 16.8MB

    const size_t need = 16384 + (size_t)ROWS * CH * 2
                      + (size_t)NBUCK * 128 * 4 + (size_t)ROWS * CH * 2;

    if (ws_size >= need) {
        k_cvt<<<dim3(2048), dim3(256), 0, stream>>>(x, xb16, W, wsb, stats16);
        k_fused_bf16<<<dim3(NBLK), dim3(256), 0, stream>>>(xb16, idx, wsb, yp, stats16);
        k_norm_bf16<<<dim3(2048), dim3(256), 0, stream>>>(yp, y, stats16, gamma, beta);
    } else {
        k_prep_fb<<<dim3(1), dim3(64), 0, stream>>>(W, wsb, stats);
        k_fused_f32<<<dim3(2048), dim3(256), 0, stream>>>(x, idx, wsb, y, stats);
        k_norm_f32<<<dim3(2048), dim3(256), 0, stream>>>(y, stats, gamma, beta);
    }
}

// Round 16
// 39.699 us; speedup vs baseline: 1.2287x; 1.0382x over previous
//
#include <hip/hip_runtime.h>

namespace {
constexpr int NPTS = 16384;
constexpr int CH   = 64;
constexpr int KNN  = 16;
constexpr int ROWS = 8 * NPTS;
constexpr float EPS = 1e-5f;
constexpr int NBLK = 512;            // k_fused grid (256 rows/block, 4 tiles/wave)
constexpr int NBUCK = 16;            // stats buckets
}

typedef __attribute__((ext_vector_type(8))) short  short8;
typedef __attribute__((ext_vector_type(4))) float  f32x4;
typedef __attribute__((ext_vector_type(4))) unsigned uint4v;
typedef __attribute__((ext_vector_type(2))) unsigned uint2v;
typedef __attribute__((ext_vector_type(4))) int    int4v;

static __device__ __forceinline__ unsigned pk_bf16(float lo, float hi) {
    unsigned r;
    asm("v_cvt_pk_bf16_f32 %0, %1, %2" : "=v"(r) : "v"(lo), "v"(hi));
    return r;
}

// Volatile packed 16-bit signed max (== relu(max) for bf16 with 0 seed).
#define PKM(D, A, B) asm volatile("v_pk_max_i16 %0, %1, %2" : "=v"(D) : "v"(A), "v"(B))

static __device__ __host__ __forceinline__ unsigned f2bf(float f) {
    unsigned u = __builtin_bit_cast(unsigned, f);
    return (u + 0x7fffu + ((u >> 16) & 1u)) >> 16;   // RNE
}

// counted drain: wait until <= N vmem ops outstanding, then fence the scheduler
#define DRAIN(N)                                                  \
    asm volatile("s_waitcnt vmcnt(" #N ")" ::: "memory");         \
    __builtin_amdgcn_sched_barrier(0)

static __device__ __forceinline__ void issue16(uint4v* v, const int* ix,
                                               unsigned off16,
                                               const unsigned* __restrict__ xb)
{
#pragma unroll
    for (int j = 0; j < 16; ++j)
        asm volatile("global_load_dwordx4 %0, %1, %2"
                     : "=v"(v[j]) : "v"((unsigned)ix[j] * 128u + off16), "s"(xb));
}

static __device__ __forceinline__ void red16(uint4v& acc, const uint4v* v)
{
#pragma unroll
    for (int j = 0; j < 16; ++j) {
        PKM(acc[0], acc[0], v[j][0]); PKM(acc[1], acc[1], v[j][1]);
        PKM(acc[2], acc[2], v[j][2]); PKM(acc[3], acc[3], v[j][3]);
    }
}

// W -> bf16 B-fragments (per-lane MFMA order).
static __device__ __forceinline__ void prep_wfrags(const float* __restrict__ W,
                                                   unsigned* __restrict__ wsb, int l)
{
    const int nq = l >> 4, nr = l & 15;
#pragma unroll
    for (int ct = 0; ct < 4; ++ct)
#pragma unroll
        for (int kh = 0; kh < 2; ++kh) {
            uint4v d;
#pragma unroll
            for (int dj = 0; dj < 4; ++dj) {
                const int k0 = kh * 32 + nq * 8 + dj * 2;
                unsigned lo = f2bf(W[(size_t)k0 * CH + ct * 16 + nr]);
                unsigned hi = f2bf(W[(size_t)(k0 + 1) * CH + ct * 16 + nr]);
                d[dj] = lo | (hi << 16);
            }
            ((uint4v*)wsb)[(ct * 2 + kh) * 64 + l] = d;
        }
}

// x (f32) -> bf16 rows of 128B, XCD-pinned (batch = blockIdx&7).
// CACHED loads (L3-resident across replays; NT costs 2-3us — r10/r12/r13).
__global__ __launch_bounds__(256)
void k_cvt(const float* __restrict__ x, unsigned* __restrict__ xb16,
           const float* __restrict__ W, unsigned* __restrict__ wsb,
           float* __restrict__ stats16)
{
    if (blockIdx.x == 0) {
        if (threadIdx.x < 64) prep_wfrags(W, wsb, threadIdx.x);
        for (int i = threadIdx.x; i < NBUCK * 128; i += 256) stats16[i] = 0.f;
    }
    const int batch = blockIdx.x & 7;
    const int chunk = blockIdx.x >> 3;
    const int lane8 = threadIdx.x & 7;
    const int rr    = threadIdx.x >> 3;
    const float*  xb = x    + (size_t)batch * NPTS * CH;
    unsigned*     ob = xb16 + (size_t)batch * NPTS * 32;
#pragma unroll
    for (int h = 0; h < 2; ++h) {
        const int row = chunk * 64 + h * 32 + rr;
        const f32x4* src = (const f32x4*)(xb + (size_t)row * CH + lane8 * 8);
        f32x4 v0 = src[0], v1 = src[1];
        uint4v d;
        d[0] = pk_bf16(v0[0], v0[1]);
        d[1] = pk_bf16(v0[2], v0[3]);
        d[2] = pk_bf16(v1[0], v1[1]);
        d[3] = pk_bf16(v1[2], v1[3]);
        *(uint4v*)(ob + (size_t)row * 32 + lane8 * 4) = d;
    }
}

// Main fused kernel: 4 tiles per wave, software-pipelined. Counted vmcnt
// drains with asm idx prefetch keep all queue positions deterministic
// (in-order vmcnt retirement, m135). sched_barrier(0) after each issue
// clause pins issue order; drain asm has "memory" so stores can't sink.
__global__ __launch_bounds__(256)
void k_fused_bf16(const unsigned* __restrict__ xb16, const int* __restrict__ idx,
                  const unsigned* __restrict__ wsb, unsigned* __restrict__ yp,
                  float* __restrict__ stats16)
{
    __shared__ __align__(16) ushort   Atile[4][16 * 64];  // per-wave, XOR-swizzled
    __shared__ __align__(16) int      Ibuf[4][256];       // per-wave 16x16 idx
    __shared__ __align__(16) unsigned Blds[2048];         // 8KB B-fragments
    __shared__ float bs1[64], bs2[64];

    const int lane  = threadIdx.x & 63;
    const int wave  = threadIdx.x >> 6;
    const int batch = blockIdx.x & 7;                     // XCD-aligned
    const int chunk = blockIdx.x >> 3;                    // 0..63

    ((uint4v*)Blds)[threadIdx.x]       = ((const uint4v*)wsb)[threadIdx.x];
    ((uint4v*)Blds)[threadIdx.x + 256] = ((const uint4v*)wsb)[threadIdx.x + 256];
    if (threadIdx.x < 64)       bs1[threadIdx.x] = 0.f;
    else if (threadIdx.x < 128) bs2[threadIdx.x - 64] = 0.f;
    __syncthreads();

    const unsigned* __restrict__ xb = xb16 + (size_t)batch * NPTS * 32;
    const int*      __restrict__ ib = idx  + (size_t)batch * NPTS * KNN;
    unsigned*       __restrict__ yb = yp   + (size_t)batch * NPTS * 32;

    const int r0 = chunk * 256 + wave * 16;               // tiles r0 + 64*t, t=0..3
    const int g8 = lane >> 3, c8 = lane & 7;
    const int c4 = lane & 15, qq = lane >> 4;
    const unsigned off16 = (unsigned)c8 * 16u;
    const int key = (c4 & 7) << 4;
    char* aw = (char*)&Atile[wave][0];

    short8 bfr[8];
#pragma unroll
    for (int f = 0; f < 8; ++f)
        bfr[f] = __builtin_bit_cast(short8, ((const uint4v*)Blds)[f * 64 + lane]);

    float sC1[4] = {0.f, 0.f, 0.f, 0.f};
    float sC2[4] = {0.f, 0.f, 0.f, 0.f};

    const int4v* Ip = (const int4v*)&Ibuf[wave][0];
    int ia[16], ibx[16];
    uint4v va[16], vb[16];
    uint4v accA, accB;
    const unsigned iqoff = (unsigned)lane * 16u;          // byte off within tile idx

#define STAGE_FROM(IQ)                                                              \
    {                                                                               \
        *(int4v*)&Ibuf[wave][lane * 4] = IQ;                                        \
        *(int4v*)&ia[0]  = Ip[g8 * 4 + 0];       *(int4v*)&ia[4]  = Ip[g8 * 4 + 1]; \
        *(int4v*)&ia[8]  = Ip[g8 * 4 + 2];       *(int4v*)&ia[12] = Ip[g8 * 4 + 3]; \
        *(int4v*)&ibx[0] = Ip[(g8 + 8) * 4 + 0]; *(int4v*)&ibx[4] = Ip[(g8 + 8) * 4 + 1]; \
        *(int4v*)&ibx[8] = Ip[(g8 + 8) * 4 + 2]; *(int4v*)&ibx[12]= Ip[(g8 + 8) * 4 + 3]; \
    }

#define LOAD_IQ(DST, RB)                                                            \
    asm volatile("global_load_dwordx4 %0, %1, %2"                                   \
                 : "=v"(DST) : "v"((unsigned)(RB) * 64u + iqoff), "s"(ib))

#define TILE_TAIL(RBASE)                                                            \
    {                                                                               \
        *(uint4v*)(aw + ((g8 * 128 + c8 * 16) ^ (g8 << 4)))       = accA;           \
        *(uint4v*)(aw + (((g8 + 8) * 128 + c8 * 16) ^ (g8 << 4))) = accB;           \
        short8 a0 = *(const short8*)(aw + ((c4 * 128 + qq * 16) ^ key));            \
        short8 a1 = *(const short8*)(aw + ((c4 * 128 + 64 + qq * 16) ^ key));       \
        f32x4 acc0 = {0,0,0,0}, acc1 = {0,0,0,0}, acc2 = {0,0,0,0}, acc3 = {0,0,0,0}; \
        acc0 = __builtin_amdgcn_mfma_f32_16x16x32_bf16(a0, bfr[0], acc0, 0, 0, 0);  \
        acc0 = __builtin_amdgcn_mfma_f32_16x16x32_bf16(a1, bfr[1], acc0, 0, 0, 0);  \
        acc1 = __builtin_amdgcn_mfma_f32_16x16x32_bf16(a0, bfr[2], acc1, 0, 0, 0);  \
        acc1 = __builtin_amdgcn_mfma_f32_16x16x32_bf16(a1, bfr[3], acc1, 0, 0, 0);  \
        acc2 = __builtin_amdgcn_mfma_f32_16x16x32_bf16(a0, bfr[4], acc2, 0, 0, 0);  \
        acc2 = __builtin_amdgcn_mfma_f32_16x16x32_bf16(a1, bfr[5], acc2, 0, 0, 0);  \
        acc3 = __builtin_amdgcn_mfma_f32_16x16x32_bf16(a0, bfr[6], acc3, 0, 0, 0);  \
        acc3 = __builtin_amdgcn_mfma_f32_16x16x32_bf16(a1, bfr[7], acc3, 0, 0, 0);  \
        unsigned* ypr = yb + (size_t)((RBASE) + qq * 4) * 32 + c4 * 2;              \
        { uint2v pr; pr[0] = pk_bf16(acc0[0], acc1[0]);                             \
          pr[1] = pk_bf16(acc2[0], acc3[0]); *(uint2v*)(ypr + 0)  = pr; }           \
        { uint2v pr; pr[0] = pk_bf16(acc0[1], acc1[1]);                             \
          pr[1] = pk_bf16(acc2[1], acc3[1]); *(uint2v*)(ypr + 32) = pr; }           \
        { uint2v pr; pr[0] = pk_bf16(acc0[2], acc1[2]);                             \
          pr[1] = pk_bf16(acc2[2], acc3[2]); *(uint2v*)(ypr + 64) = pr; }           \
        { uint2v pr; pr[0] = pk_bf16(acc0[3], acc1[3]);                             \
          pr[1] = pk_bf16(acc2[3], acc3[3]); *(uint2v*)(ypr + 96) = pr; }           \
        sC1[0] += (acc0[0] + acc0[1]) + (acc0[2] + acc0[3]);                        \
        sC2[0] += (acc0[0]*acc0[0] + acc0[1]*acc0[1]) + (acc0[2]*acc0[2] + acc0[3]*acc0[3]); \
        sC1[1] += (acc1[0] + acc1[1]) + (acc1[2] + acc1[3]);                        \
        sC2[1] += (acc1[0]*acc1[0] + acc1[1]*acc1[1]) + (acc1[2]*acc1[2] + acc1[3]*acc1[3]); \
        sC1[2] += (acc2[0] + acc2[1]) + (acc2[2] + acc2[3]);                        \
        sC2[2] += (acc2[0]*acc2[0] + acc2[1]*acc2[1]) + (acc2[2]*acc2[2] + acc2[3]*acc2[3]); \
        sC1[3] += (acc3[0] + acc3[1]) + (acc3[2] + acc3[3]);                        \
        sC2[3] += (acc3[0]*acc3[0] + acc3[1]*acc3[1]) + (acc3[2]*acc3[2] + acc3[3]*acc3[3]); \
    }

#define RESET_ACC()                                                                 \
    accA[0] = accA[1] = accA[2] = accA[3] = 0u;                                     \
    accB[0] = accB[1] = accB[2] = accB[3] = 0u

    // ---- prologue: tile0
    int4v iq0 = ((const int4v*)(ib + (size_t)r0 * KNN))[lane];   // compiler-waited
    STAGE_FROM(iq0);
    issue16(va, ia, off16, xb);
    issue16(vb, ibx, off16, xb);
    int4v iq1, iq2, iq3;
    LOAD_IQ(iq1, r0 + 64);
    __builtin_amdgcn_sched_barrier(0);

    // ---- t=0: queue [g0x32, iq1]
    DRAIN(1);                       // g0 done
    RESET_ACC(); red16(accA, va); red16(accB, vb);
    DRAIN(0);                       // iq1 done (free by now)
    STAGE_FROM(iq1);
    issue16(va, ia, off16, xb);
    issue16(vb, ibx, off16, xb);
    LOAD_IQ(iq2, r0 + 128);
    __builtin_amdgcn_sched_barrier(0);
    TILE_TAIL(r0)                   // 4 stores -> queue [g1x32, iq2, st0x4]

    // ---- t=1
    DRAIN(5);                       // g1 done (iq2 + st0x4 newer)
    RESET_ACC(); red16(accA, va); red16(accB, vb);
    DRAIN(4);                       // iq2 done (st0x4 newer)
    STAGE_FROM(iq2);
    issue16(va, ia, off16, xb);
    issue16(vb, ibx, off16, xb);
    LOAD_IQ(iq3, r0 + 192);
    __builtin_amdgcn_sched_barrier(0);
    TILE_TAIL(r0 + 64)              // queue [g2x32, iq3, st1x4]

    // ---- t=2
    DRAIN(5);                       // g2 done
    RESET_ACC(); red16(accA, va); red16(accB, vb);
    DRAIN(4);                       // iq3 done
    STAGE_FROM(iq3);
    issue16(va, ia, off16, xb);
    issue16(vb, ibx, off16, xb);
    __builtin_amdgcn_sched_barrier(0);
    TILE_TAIL(r0 + 128)             // queue [g3x32, st2x4]

    // ---- t=3
    DRAIN(4);                       // g3 done (st2x4 newer)
    RESET_ACC(); red16(accA, va); red16(accB, vb);
    TILE_TAIL(r0 + 192)

#undef STAGE_FROM
#undef LOAD_IQ
#undef TILE_TAIL
#undef RESET_ACC

    // ---- stats: shuffle -> block LDS -> one bucketed global atomic per thread
#pragma unroll
    for (int ct = 0; ct < 4; ++ct) {
        float s1 = sC1[ct], s2 = sC2[ct];
        s1 += __shfl_xor(s1, 16); s1 += __shfl_xor(s1, 32);
        s2 += __shfl_xor(s2, 16); s2 += __shfl_xor(s2, 32);
        if (lane < 16) {
            atomicAdd(&bs1[ct * 16 + lane], s1);
            atomicAdd(&bs2[ct * 16 + lane], s2);
        }
    }
    __syncthreads();
    if (threadIdx.x < 128)
        atomicAdd(&stats16[(blockIdx.x & (NBUCK - 1)) * 128 + threadIdx.x],
                  (threadIdx.x < 64) ? bs1[threadIdx.x] : bs2[threadIdx.x - 64]);
}

// bf16-y normalize; folds the 16 stats buckets (8KB) in the header.
__global__ __launch_bounds__(256)
void k_norm_bf16(const unsigned* __restrict__ yp, float* __restrict__ y,
                 const float* __restrict__ stats16,
                 const float* __restrict__ gamma, const float* __restrict__ beta)
{
    __shared__ float s[CH], b[CH];
    if (threadIdx.x < CH) {
        const int l = threadIdx.x;
        float s1 = 0.f, s2 = 0.f;
#pragma unroll
        for (int k = 0; k < NBUCK; ++k) {
            s1 += stats16[k * 128 + l];
            s2 += stats16[k * 128 + 64 + l];
        }
        const float inv_n = 1.0f / (float)ROWS;
        float mean = s1 * inv_n;
        float var  = s2 * inv_n - mean * mean;
        float sc   = gamma[l] * rsqrtf(var + EPS);
        s[l] = sc;
        b[l] = beta[l] - mean * sc;
    }
    __syncthreads();

    const size_t ntot = (size_t)ROWS * 16;
    size_t i = (size_t)blockIdx.x * blockDim.x + threadIdx.x;
    const size_t stride = (size_t)gridDim.x * blockDim.x;
    for (; i < ntot; i += stride) {
        const size_t row = i >> 4;
        const int c4 = (int)i & 15;
        uint2v p = *(const uint2v*)(yp + row * 32 + c4 * 2);
        float v0 = __uint_as_float(p[0] << 16);
        float v1 = __uint_as_float(p[0] & 0xffff0000u);
        float v2 = __uint_as_float(p[1] << 16);
        float v3 = __uint_as_float(p[1] & 0xffff0000u);
        float* yr = y + row * CH;
        yr[c4]      = fmaf(v0, s[c4],      b[c4]);
        yr[c4 + 16] = fmaf(v1, s[c4 + 16], b[c4 + 16]);
        yr[c4 + 32] = fmaf(v2, s[c4 + 32], b[c4 + 32]);
        yr[c4 + 48] = fmaf(v3, s[c4 + 48], b[c4 + 48]);
    }
}

// ---- fallback path (ws too small): round-2 f32 kernel + atomic stats ----
__global__ __launch_bounds__(64)
void k_prep_fb(const float* __restrict__ W, unsigned* __restrict__ wsb,
               float* __restrict__ stats)
{
    if (threadIdx.x < 64) {
        stats[threadIdx.x] = 0.f;
        stats[64 + threadIdx.x] = 0.f;
        prep_wfrags(W, wsb, threadIdx.x);
    }
}

__global__ __launch_bounds__(256)
void k_fused_f32(const float* __restrict__ x, const int* __restrict__ idx,
                 const unsigned* __restrict__ wsb, float* __restrict__ y,
                 float* __restrict__ stats)
{
    __shared__ __align__(16) ushort Atile[4][16 * 64];
    __shared__ __align__(16) int    Ibuf[4][256];
    __shared__ float bs1[64], bs2[64];

    const int lane  = threadIdx.x & 63;
    const int wave  = threadIdx.x >> 6;
    const int batch = blockIdx.x & 7;
    const int chunk = blockIdx.x >> 3;

    if (threadIdx.x < 64)       bs1[threadIdx.x] = 0.f;
    else if (threadIdx.x < 128) bs2[threadIdx.x - 64] = 0.f;
    __syncthreads();

    const int r0 = chunk * 64 + wave * 16;
    const float* __restrict__ xb = x   + (size_t)batch * NPTS * CH;
    const int*   __restrict__ ib = idx + (size_t)batch * NPTS * KNN;
    float*       __restrict__ yb = y   + (size_t)batch * NPTS * CH;

    const int c4 = lane & 15;
    const int qq = lane >> 4;

    int4v iq = ((const int4v*)(ib + (size_t)r0 * KNN))[lane];
    *(int4v*)&Ibuf[wave][lane * 4] = iq;

    short8 bfr[8];
#pragma unroll
    for (int f = 0; f < 8; ++f)
        bfr[f] = __builtin_bit_cast(short8, ((const uint4v*)wsb)[f * 64 + lane]);

    char* aw = (char*)&Atile[wave][0];
    const f32x4* xb4 = (const f32x4*)xb;

#pragma unroll
    for (int g = 0; g < 4; ++g) {
        const int row = 4 * g + qq;
        const int* ip = &Ibuf[wave][row * KNN];
        f32x4 acc = {0.f, 0.f, 0.f, 0.f};
#pragma unroll
        for (int j = 0; j < KNN; ++j) {
            const int n = ip[j];
            f32x4 v = xb4[n * 16 + c4];
            acc[0] = fmaxf(acc[0], v[0]);
            acc[1] = fmaxf(acc[1], v[1]);
            acc[2] = fmaxf(acc[2], v[2]);
            acc[3] = fmaxf(acc[3], v[3]);
        }
        uint2v pw;
        pw[0] = pk_bf16(acc[0], acc[1]);
        pw[1] = pk_bf16(acc[2], acc[3]);
        const int wb = ((row * 128) + c4 * 8) ^ ((row & 7) << 4);
        *(uint2v*)(aw + wb) = pw;
    }

    const int key = (c4 & 7) << 4;
    short8 a0 = *(const short8*)(aw + ((c4 * 128 + qq * 16) ^ key));
    short8 a1 = *(const short8*)(aw + ((c4 * 128 + 64 + qq * 16) ^ key));

    f32x4 acc0 = {0,0,0,0}, acc1 = {0,0,0,0}, acc2 = {0,0,0,0}, acc3 = {0,0,0,0};
    acc0 = __builtin_amdgcn_mfma_f32_16x16x32_bf16(a0, bfr[0], acc0, 0, 0, 0);
    acc0 = __builtin_amdgcn_mfma_f32_16x16x32_bf16(a1, bfr[1], acc0, 0, 0, 0);
    acc1 = __builtin_amdgcn_mfma_f32_16x16x32_bf16(a0, bfr[2], acc1, 0, 0, 0);
    acc1 = __builtin_amdgcn_mfma_f32_16x16x32_bf16(a1, bfr[3], acc1, 0, 0, 0);
    acc2 = __builtin_amdgcn_mfma_f32_16x16x32_bf16(a0, bfr[4], acc2, 0, 0, 0);
    acc2 = __builtin_amdgcn_mfma_f32_16x16x32_bf16(a1, bfr[5], acc2, 0, 0, 0);
    acc3 = __builtin_amdgcn_mfma_f32_16x16x32_bf16(a0, bfr[6], acc3, 0, 0, 0);
    acc3 = __builtin_amdgcn_mfma_f32_16x16x32_bf16(a1, bfr[7], acc3, 0, 0, 0);

    float* yrow = yb + (size_t)(r0 + qq * 4) * CH + c4;
#define DO_CT(CT, ACC)                                                              \
    {                                                                               \
        yrow[0 * CH + CT * 16] = ACC[0];                                            \
        yrow[1 * CH + CT * 16] = ACC[1];                                            \
        yrow[2 * CH + CT * 16] = ACC[2];                                            \
        yrow[3 * CH + CT * 16] = ACC[3];                                            \
        float s1 = (ACC[0] + ACC[1]) + (ACC[2] + ACC[3]);                           \
        float s2 = (ACC[0]*ACC[0] + ACC[1]*ACC[1]) + (ACC[2]*ACC[2] + ACC[3]*ACC[3]); \
        s1 += __shfl_xor(s1, 16); s1 += __shfl_xor(s1, 32);                         \
        s2 += __shfl_xor(s2, 16); s2 += __shfl_xor(s2, 32);                         \
        if (lane < 16) {                                                            \
            atomicAdd(&bs1[CT * 16 + lane], s1);                                    \
            atomicAdd(&bs2[CT * 16 + lane], s2);                                    \
        }                                                                           \
    }
    DO_CT(0, acc0) DO_CT(1, acc1) DO_CT(2, acc2) DO_CT(3, acc3)
#undef DO_CT

    __syncthreads();
    if (threadIdx.x < 64)        atomicAdd(&stats[threadIdx.x], bs1[threadIdx.x]);
    else if (threadIdx.x < 128)  atomicAdd(&stats[threadIdx.x], bs2[threadIdx.x - 64]);
}

// fallback normalize: in-place on f32 y, stats[128] source
__global__ __launch_bounds__(256)
void k_norm_f32(float* __restrict__ y, const float* __restrict__ stats,
                const float* __restrict__ gamma, const float* __restrict__ beta)
{
    __shared__ float s[CH], b[CH];
    if (threadIdx.x < CH) {
        const int l = threadIdx.x;
        const float inv_n = 1.0f / (float)ROWS;
        float mean = stats[l] * inv_n;
        float var  = stats[64 + l] * inv_n - mean * mean;
        float sc   = gamma[l] * rsqrtf(var + EPS);
        s[l] = sc;
        b[l] = beta[l] - mean * sc;
    }
    __syncthreads();

    f32x4* p = (f32x4*)y;
    const size_t ntot = (size_t)ROWS * CH / 4;
    size_t i = (size_t)blockIdx.x * blockDim.x + threadIdx.x;
    const size_t stride = (size_t)gridDim.x * blockDim.x;
    for (; i < ntot; i += stride) {
        f32x4 v = p[i];
        const int c0 = ((int)i & 15) * 4;
        v[0] = fmaf(v[0], s[c0],     b[c0]);
        v[1] = fmaf(v[1], s[c0 + 1], b[c0 + 1]);
        v[2] = fmaf(v[2], s[c0 + 2], b[c0 + 2]);
        v[3] = fmaf(v[3], s[c0 + 3], b[c0 + 3]);
        p[i] = v;
    }
}

extern "C" void kernel_launch(void* const* d_in, const int* in_sizes, int n_in,
                              void* d_out, int out_size, void* d_ws, size_t ws_size,
                              hipStream_t stream)
{
    const float* x     = (const float*)d_in[0];
    const int*   idx   = (const int*)d_in[1];
    const float* W     = (const float*)d_in[2];
    const float* gamma = (const float*)d_in[3];
    const float* beta  = (const float*)d_in[4];

    float*    y       = (float*)d_out;
    float*    stats   = (float*)d_ws;                     // fallback only
    unsigned* wsb     = (unsigned*)(stats + 256);         // 8KB B-fragments
    char*     base    = (char*)d_ws + 16384;
    unsigned* xb16    = (unsigned*)base;                                 // 16.8MB
    float*    stats16 = (float*)(base + (size_t)ROWS * CH * 2);          // 8KB
    unsigned* yp      = (unsigned*)(stats16 + NBUCK * 128);              // 16.8MB

    const size_t need = 16384 + (size_t)ROWS * CH * 2
                      + (size_t)NBUCK * 128 * 4 + (size_t)ROWS * CH * 2;

    if (ws_size >= need) {
        k_cvt<<<dim3(2048), dim3(256), 0, stream>>>(x, xb16, W, wsb, stats16);
        k_fused_bf16<<<dim3(NBLK), dim3(256), 0, stream>>>(xb16, idx, wsb, yp, stats16);
        k_norm_bf16<<<dim3(2048), dim3(256), 0, stream>>>(yp, y, stats16, gamma, beta);
    } else {
        k_prep_fb<<<dim3(1), dim3(64), 0, stream>>>(W, wsb, stats);
        k_fused_f32<<<dim3(2048), dim3(256), 0, stream>>>(x, idx, wsb, y, stats);
        k_norm_f32<<<dim3(2048), dim3(256), 0, stream>>>(y, stats, gamma, beta);
    }
}

// Round 17
// 39.603 us; speedup vs baseline: 1.2317x; 1.0024x over previous
//
#include <hip/hip_runtime.h>

namespace {
constexpr int NPTS = 16384;
constexpr int CH   = 64;
constexpr int KNN  = 16;
constexpr int ROWS = 8 * NPTS;
constexpr float EPS = 1e-5f;
constexpr int NBLK = 512;            // k_fused grid (256 rows/block, 4 tiles/wave)
constexpr int NBUCK = 16;            // stats buckets
}

typedef __attribute__((ext_vector_type(8))) short  short8;
typedef __attribute__((ext_vector_type(4))) float  f32x4;
typedef __attribute__((ext_vector_type(4))) unsigned uint4v;
typedef __attribute__((ext_vector_type(2))) unsigned uint2v;
typedef __attribute__((ext_vector_type(4))) int    int4v;

static __device__ __forceinline__ unsigned pk_bf16(float lo, float hi) {
    unsigned r;
    asm("v_cvt_pk_bf16_f32 %0, %1, %2" : "=v"(r) : "v"(lo), "v"(hi));
    return r;
}

// Volatile packed 16-bit signed max (== relu(max) for bf16 with 0 seed).
#define PKM(D, A, B) asm volatile("v_pk_max_i16 %0, %1, %2" : "=v"(D) : "v"(A), "v"(B))

static __device__ __host__ __forceinline__ unsigned f2bf(float f) {
    unsigned u = __builtin_bit_cast(unsigned, f);
    return (u + 0x7fffu + ((u >> 16) & 1u)) >> 16;   // RNE
}

// counted drain: wait until <= N vmem ops outstanding, then fence the scheduler
#define DRAIN(N)                                                  \
    asm volatile("s_waitcnt vmcnt(" #N ")" ::: "memory");         \
    __builtin_amdgcn_sched_barrier(0)

static __device__ __forceinline__ void issue16(uint4v* v, const int* ix,
                                               unsigned off16,
                                               const unsigned* __restrict__ xb)
{
#pragma unroll
    for (int j = 0; j < 16; ++j)
        asm volatile("global_load_dwordx4 %0, %1, %2"
                     : "=v"(v[j]) : "v"((unsigned)ix[j] * 128u + off16), "s"(xb));
}

static __device__ __forceinline__ void red16(uint4v& acc, const uint4v* v)
{
#pragma unroll
    for (int j = 0; j < 16; ++j) {
        PKM(acc[0], acc[0], v[j][0]); PKM(acc[1], acc[1], v[j][1]);
        PKM(acc[2], acc[2], v[j][2]); PKM(acc[3], acc[3], v[j][3]);
    }
}

// W -> bf16 B-fragments (per-lane MFMA order).
static __device__ __forceinline__ void prep_wfrags(const float* __restrict__ W,
                                                   unsigned* __restrict__ wsb, int l)
{
    const int nq = l >> 4, nr = l & 15;
#pragma unroll
    for (int ct = 0; ct < 4; ++ct)
#pragma unroll
        for (int kh = 0; kh < 2; ++kh) {
            uint4v d;
#pragma unroll
            for (int dj = 0; dj < 4; ++dj) {
                const int k0 = kh * 32 + nq * 8 + dj * 2;
                unsigned lo = f2bf(W[(size_t)k0 * CH + ct * 16 + nr]);
                unsigned hi = f2bf(W[(size_t)(k0 + 1) * CH + ct * 16 + nr]);
                d[dj] = lo | (hi << 16);
            }
            ((uint4v*)wsb)[(ct * 2 + kh) * 64 + l] = d;
        }
}

// x (f32) -> bf16 rows of 128B, XCD-pinned (batch = blockIdx&7).
// CACHED loads (NT loads cost 2-3us — r10/r12/r13 lessons).
__global__ __launch_bounds__(256)
void k_cvt(const float* __restrict__ x, unsigned* __restrict__ xb16,
           const float* __restrict__ W, unsigned* __restrict__ wsb,
           float* __restrict__ stats16)
{
    if (blockIdx.x == 0) {
        if (threadIdx.x < 64) prep_wfrags(W, wsb, threadIdx.x);
        for (int i = threadIdx.x; i < NBUCK * 128; i += 256) stats16[i] = 0.f;
    }
    const int batch = blockIdx.x & 7;
    const int chunk = blockIdx.x >> 3;
    const int lane8 = threadIdx.x & 7;
    const int rr    = threadIdx.x >> 3;
    const float*  xb = x    + (size_t)batch * NPTS * CH;
    unsigned*     ob = xb16 + (size_t)batch * NPTS * 32;
#pragma unroll
    for (int h = 0; h < 2; ++h) {
        const int row = chunk * 64 + h * 32 + rr;
        const f32x4* src = (const f32x4*)(xb + (size_t)row * CH + lane8 * 8);
        f32x4 v0 = src[0], v1 = src[1];
        uint4v d;
        d[0] = pk_bf16(v0[0], v0[1]);
        d[1] = pk_bf16(v0[2], v0[3]);
        d[2] = pk_bf16(v1[0], v1[1]);
        d[3] = pk_bf16(v1[2], v1[3]);
        *(uint4v*)(ob + (size_t)row * 32 + lane8 * 4) = d;
    }
}

// Main fused kernel: 4 tiles per wave, software-pipelined (r16 structure,
// unchanged). Counted vmcnt drains; deterministic queue positions.
__global__ __launch_bounds__(256)
void k_fused_bf16(const unsigned* __restrict__ xb16, const int* __restrict__ idx,
                  const unsigned* __restrict__ wsb, unsigned* __restrict__ yp,
                  float* __restrict__ stats16)
{
    __shared__ __align__(16) ushort   Atile[4][16 * 64];  // per-wave, XOR-swizzled
    __shared__ __align__(16) int      Ibuf[4][256];       // per-wave 16x16 idx
    __shared__ __align__(16) unsigned Blds[2048];         // 8KB B-fragments
    __shared__ float bs1[64], bs2[64];

    const int lane  = threadIdx.x & 63;
    const int wave  = threadIdx.x >> 6;
    const int batch = blockIdx.x & 7;                     // XCD-aligned
    const int chunk = blockIdx.x >> 3;                    // 0..63

    ((uint4v*)Blds)[threadIdx.x]       = ((const uint4v*)wsb)[threadIdx.x];
    ((uint4v*)Blds)[threadIdx.x + 256] = ((const uint4v*)wsb)[threadIdx.x + 256];
    if (threadIdx.x < 64)       bs1[threadIdx.x] = 0.f;
    else if (threadIdx.x < 128) bs2[threadIdx.x - 64] = 0.f;
    __syncthreads();

    const unsigned* __restrict__ xb = xb16 + (size_t)batch * NPTS * 32;
    const int*      __restrict__ ib = idx  + (size_t)batch * NPTS * KNN;
    unsigned*       __restrict__ yb = yp   + (size_t)batch * NPTS * 32;

    const int r0 = chunk * 256 + wave * 16;               // tiles r0 + 64*t, t=0..3
    const int g8 = lane >> 3, c8 = lane & 7;
    const int c4 = lane & 15, qq = lane >> 4;
    const unsigned off16 = (unsigned)c8 * 16u;
    const int key = (c4 & 7) << 4;
    char* aw = (char*)&Atile[wave][0];

    short8 bfr[8];
#pragma unroll
    for (int f = 0; f < 8; ++f)
        bfr[f] = __builtin_bit_cast(short8, ((const uint4v*)Blds)[f * 64 + lane]);

    float sC1[4] = {0.f, 0.f, 0.f, 0.f};
    float sC2[4] = {0.f, 0.f, 0.f, 0.f};

    const int4v* Ip = (const int4v*)&Ibuf[wave][0];
    int ia[16], ibx[16];
    uint4v va[16], vb[16];
    uint4v accA, accB;
    const unsigned iqoff = (unsigned)lane * 16u;          // byte off within tile idx

#define STAGE_FROM(IQ)                                                              \
    {                                                                               \
        *(int4v*)&Ibuf[wave][lane * 4] = IQ;                                        \
        *(int4v*)&ia[0]  = Ip[g8 * 4 + 0];       *(int4v*)&ia[4]  = Ip[g8 * 4 + 1]; \
        *(int4v*)&ia[8]  = Ip[g8 * 4 + 2];       *(int4v*)&ia[12] = Ip[g8 * 4 + 3]; \
        *(int4v*)&ibx[0] = Ip[(g8 + 8) * 4 + 0]; *(int4v*)&ibx[4] = Ip[(g8 + 8) * 4 + 1]; \
        *(int4v*)&ibx[8] = Ip[(g8 + 8) * 4 + 2]; *(int4v*)&ibx[12]= Ip[(g8 + 8) * 4 + 3]; \
    }

#define LOAD_IQ(DST, RB)                                                            \
    asm volatile("global_load_dwordx4 %0, %1, %2"                                   \
                 : "=v"(DST) : "v"((unsigned)(RB) * 64u + iqoff), "s"(ib))

#define TILE_TAIL(RBASE)                                                            \
    {                                                                               \
        *(uint4v*)(aw + ((g8 * 128 + c8 * 16) ^ (g8 << 4)))       = accA;           \
        *(uint4v*)(aw + (((g8 + 8) * 128 + c8 * 16) ^ (g8 << 4))) = accB;           \
        short8 a0 = *(const short8*)(aw + ((c4 * 128 + qq * 16) ^ key));            \
        short8 a1 = *(const short8*)(aw + ((c4 * 128 + 64 + qq * 16) ^ key));       \
        f32x4 acc0 = {0,0,0,0}, acc1 = {0,0,0,0}, acc2 = {0,0,0,0}, acc3 = {0,0,0,0}; \
        acc0 = __builtin_amdgcn_mfma_f32_16x16x32_bf16(a0, bfr[0], acc0, 0, 0, 0);  \
        acc0 = __builtin_amdgcn_mfma_f32_16x16x32_bf16(a1, bfr[1], acc0, 0, 0, 0);  \
        acc1 = __builtin_amdgcn_mfma_f32_16x16x32_bf16(a0, bfr[2], acc1, 0, 0, 0);  \
        acc1 = __builtin_amdgcn_mfma_f32_16x16x32_bf16(a1, bfr[3], acc1, 0, 0, 0);  \
        acc2 = __builtin_amdgcn_mfma_f32_16x16x32_bf16(a0, bfr[4], acc2, 0, 0, 0);  \
        acc2 = __builtin_amdgcn_mfma_f32_16x16x32_bf16(a1, bfr[5], acc2, 0, 0, 0);  \
        acc3 = __builtin_amdgcn_mfma_f32_16x16x32_bf16(a0, bfr[6], acc3, 0, 0, 0);  \
        acc3 = __builtin_amdgcn_mfma_f32_16x16x32_bf16(a1, bfr[7], acc3, 0, 0, 0);  \
        unsigned* ypr = yb + (size_t)((RBASE) + qq * 4) * 32 + c4 * 2;              \
        { uint2v pr; pr[0] = pk_bf16(acc0[0], acc1[0]);                             \
          pr[1] = pk_bf16(acc2[0], acc3[0]); *(uint2v*)(ypr + 0)  = pr; }           \
        { uint2v pr; pr[0] = pk_bf16(acc0[1], acc1[1]);                             \
          pr[1] = pk_bf16(acc2[1], acc3[1]); *(uint2v*)(ypr + 32) = pr; }           \
        { uint2v pr; pr[0] = pk_bf16(acc0[2], acc1[2]);                             \
          pr[1] = pk_bf16(acc2[2], acc3[2]); *(uint2v*)(ypr + 64) = pr; }           \
        { uint2v pr; pr[0] = pk_bf16(acc0[3], acc1[3]);                             \
          pr[1] = pk_bf16(acc2[3], acc3[3]); *(uint2v*)(ypr + 96) = pr; }           \
        sC1[0] += (acc0[0] + acc0[1]) + (acc0[2] + acc0[3]);                        \
        sC2[0] += (acc0[0]*acc0[0] + acc0[1]*acc0[1]) + (acc0[2]*acc0[2] + acc0[3]*acc0[3]); \
        sC1[1] += (acc1[0] + acc1[1]) + (acc1[2] + acc1[3]);                        \
        sC2[1] += (acc1[0]*acc1[0] + acc1[1]*acc1[1]) + (acc1[2]*acc1[2] + acc1[3]*acc1[3]); \
        sC1[2] += (acc2[0] + acc2[1]) + (acc2[2] + acc2[3]);                        \
        sC2[2] += (acc2[0]*acc2[0] + acc2[1]*acc2[1]) + (acc2[2]*acc2[2] + acc2[3]*acc2[3]); \
        sC1[3] += (acc3[0] + acc3[1]) + (acc3[2] + acc3[3]);                        \
        sC2[3] += (acc3[0]*acc3[0] + acc3[1]*acc3[1]) + (acc3[2]*acc3[2] + acc3[3]*acc3[3]); \
    }

#define RESET_ACC()                                                                 \
    accA[0] = accA[1] = accA[2] = accA[3] = 0u;                                     \
    accB[0] = accB[1] = accB[2] = accB[3] = 0u

    // ---- prologue: tile0
    int4v iq0 = ((const int4v*)(ib + (size_t)r0 * KNN))[lane];   // compiler-waited
    STAGE_FROM(iq0);
    issue16(va, ia, off16, xb);
    issue16(vb, ibx, off16, xb);
    int4v iq1, iq2, iq3;
    LOAD_IQ(iq1, r0 + 64);
    __builtin_amdgcn_sched_barrier(0);

    // ---- t=0: queue [g0x32, iq1]
    DRAIN(1);
    RESET_ACC(); red16(accA, va); red16(accB, vb);
    DRAIN(0);
    STAGE_FROM(iq1);
    issue16(va, ia, off16, xb);
    issue16(vb, ibx, off16, xb);
    LOAD_IQ(iq2, r0 + 128);
    __builtin_amdgcn_sched_barrier(0);
    TILE_TAIL(r0)                   // queue [g1x32, iq2, st0x4]

    // ---- t=1
    DRAIN(5);
    RESET_ACC(); red16(accA, va); red16(accB, vb);
    DRAIN(4);
    STAGE_FROM(iq2);
    issue16(va, ia, off16, xb);
    issue16(vb, ibx, off16, xb);
    LOAD_IQ(iq3, r0 + 192);
    __builtin_amdgcn_sched_barrier(0);
    TILE_TAIL(r0 + 64)              // queue [g2x32, iq3, st1x4]

    // ---- t=2
    DRAIN(5);
    RESET_ACC(); red16(accA, va); red16(accB, vb);
    DRAIN(4);
    STAGE_FROM(iq3);
    issue16(va, ia, off16, xb);
    issue16(vb, ibx, off16, xb);
    __builtin_amdgcn_sched_barrier(0);
    TILE_TAIL(r0 + 128)             // queue [g3x32, st2x4]

    // ---- t=3
    DRAIN(4);
    RESET_ACC(); red16(accA, va); red16(accB, vb);
    TILE_TAIL(r0 + 192)

#undef STAGE_FROM
#undef LOAD_IQ
#undef TILE_TAIL
#undef RESET_ACC

    // ---- stats: shuffle -> block LDS -> one bucketed global atomic per thread
#pragma unroll
    for (int ct = 0; ct < 4; ++ct) {
        float s1 = sC1[ct], s2 = sC2[ct];
        s1 += __shfl_xor(s1, 16); s1 += __shfl_xor(s1, 32);
        s2 += __shfl_xor(s2, 16); s2 += __shfl_xor(s2, 32);
        if (lane < 16) {
            atomicAdd(&bs1[ct * 16 + lane], s1);
            atomicAdd(&bs2[ct * 16 + lane], s2);
        }
    }
    __syncthreads();
    if (threadIdx.x < 128)
        atomicAdd(&stats16[(blockIdx.x & (NBUCK - 1)) * 128 + threadIdx.x],
                  (threadIdx.x < 64) ? bs1[threadIdx.x] : bs2[threadIdx.x - 64]);
}

// bf16-y normalize. Thread i -> (row = i>>4, c0 = (i&15)*4): 4 dword loads
// (stride 8B, L2/L3-served) -> one fully-coalesced f32x4 store (wave covers
// 4 rows x 256B = 1KB contiguous per store instruction).
__global__ __launch_bounds__(256)
void k_norm_bf16(const unsigned* __restrict__ yp, float* __restrict__ y,
                 const float* __restrict__ stats16,
                 const float* __restrict__ gamma, const float* __restrict__ beta)
{
    __shared__ float s[CH], b[CH];
    if (threadIdx.x < CH) {
        const int l = threadIdx.x;
        float s1 = 0.f, s2 = 0.f;
#pragma unroll
        for (int k = 0; k < NBUCK; ++k) {
            s1 += stats16[k * 128 + l];
            s2 += stats16[k * 128 + 64 + l];
        }
        const float inv_n = 1.0f / (float)ROWS;
        float mean = s1 * inv_n;
        float var  = s2 * inv_n - mean * mean;
        float sc   = gamma[l] * rsqrtf(var + EPS);
        s[l] = sc;
        b[l] = beta[l] - mean * sc;
    }
    __syncthreads();

    const size_t ntot = (size_t)ROWS * 16;
    size_t i = (size_t)blockIdx.x * blockDim.x + threadIdx.x;
    const size_t stride = (size_t)gridDim.x * blockDim.x;
    for (; i < ntot; i += stride) {
        const size_t row = i >> 4;
        const int c0 = ((int)i & 15) * 4;                 // 4 consecutive channels
        const int half = c0 >> 4;                         // 0..3
        const int widx = ((c0 & 15) * 2) + (half >> 1);   // word stride 2
        const int hi   = half & 1;                        // lo/hi bf16 of each word
        const unsigned* ypr = yp + row * 32 + widx;
        unsigned w0 = ypr[0], w1 = ypr[2], w2 = ypr[4], w3 = ypr[6];
        const unsigned sh = hi ? 0u : 16u;                // lo -> <<16; hi -> mask
        f32x4 v;
        v[0] = __uint_as_float(hi ? (w0 & 0xffff0000u) : (w0 << 16));
        v[1] = __uint_as_float(hi ? (w1 & 0xffff0000u) : (w1 << 16));
        v[2] = __uint_as_float(hi ? (w2 & 0xffff0000u) : (w2 << 16));
        v[3] = __uint_as_float(hi ? (w3 & 0xffff0000u) : (w3 << 16));
        (void)sh;
        v[0] = fmaf(v[0], s[c0],     b[c0]);
        v[1] = fmaf(v[1], s[c0 + 1], b[c0 + 1]);
        v[2] = fmaf(v[2], s[c0 + 2], b[c0 + 2]);
        v[3] = fmaf(v[3], s[c0 + 3], b[c0 + 3]);
        *(f32x4*)(y + row * CH + c0) = v;
    }
}

// ---- fallback path (ws too small): round-2 f32 kernel + atomic stats ----
__global__ __launch_bounds__(64)
void k_prep_fb(const float* __restrict__ W, unsigned* __restrict__ wsb,
               float* __restrict__ stats)
{
    if (threadIdx.x < 64) {
        stats[threadIdx.x] = 0.f;
        stats[64 + threadIdx.x] = 0.f;
        prep_wfrags(W, wsb, threadIdx.x);
    }
}

__global__ __launch_bounds__(256)
void k_fused_f32(const float* __restrict__ x, const int* __restrict__ idx,
                 const unsigned* __restrict__ wsb, float* __restrict__ y,
                 float* __restrict__ stats)
{
    __shared__ __align__(16) ushort Atile[4][16 * 64];
    __shared__ __align__(16) int    Ibuf[4][256];
    __shared__ float bs1[64], bs2[64];

    const int lane  = threadIdx.x & 63;
    const int wave  = threadIdx.x >> 6;
    const int batch = blockIdx.x & 7;
    const int chunk = blockIdx.x >> 3;

    if (threadIdx.x < 64)       bs1[threadIdx.x] = 0.f;
    else if (threadIdx.x < 128) bs2[threadIdx.x - 64] = 0.f;
    __syncthreads();

    const int r0 = chunk * 64 + wave * 16;
    const float* __restrict__ xb = x   + (size_t)batch * NPTS * CH;
    const int*   __restrict__ ib = idx + (size_t)batch * NPTS * KNN;
    float*       __restrict__ yb = y   + (size_t)batch * NPTS * CH;

    const int c4 = lane & 15;
    const int qq = lane >> 4;

    int4v iq = ((const int4v*)(ib + (size_t)r0 * KNN))[lane];
    *(int4v*)&Ibuf[wave][lane * 4] = iq;

    short8 bfr[8];
#pragma unroll
    for (int f = 0; f < 8; ++f)
        bfr[f] = __builtin_bit_cast(short8, ((const uint4v*)wsb)[f * 64 + lane]);

    char* aw = (char*)&Atile[wave][0];
    const f32x4* xb4 = (const f32x4*)xb;

#pragma unroll
    for (int g = 0; g < 4; ++g) {
        const int row = 4 * g + qq;
        const int* ip = &Ibuf[wave][row * KNN];
        f32x4 acc = {0.f, 0.f, 0.f, 0.f};
#pragma unroll
        for (int j = 0; j < KNN; ++j) {
            const int n = ip[j];
            f32x4 v = xb4[n * 16 + c4];
            acc[0] = fmaxf(acc[0], v[0]);
            acc[1] = fmaxf(acc[1], v[1]);
            acc[2] = fmaxf(acc[2], v[2]);
            acc[3] = fmaxf(acc[3], v[3]);
        }
        uint2v pw;
        pw[0] = pk_bf16(acc[0], acc[1]);
        pw[1] = pk_bf16(acc[2], acc[3]);
        const int wb = ((row * 128) + c4 * 8) ^ ((row & 7) << 4);
        *(uint2v*)(aw + wb) = pw;
    }

    const int key = (c4 & 7) << 4;
    short8 a0 = *(const short8*)(aw + ((c4 * 128 + qq * 16) ^ key));
    short8 a1 = *(const short8*)(aw + ((c4 * 128 + 64 + qq * 16) ^ key));

    f32x4 acc0 = {0,0,0,0}, acc1 = {0,0,0,0}, acc2 = {0,0,0,0}, acc3 = {0,0,0,0};
    acc0 = __builtin_amdgcn_mfma_f32_16x16x32_bf16(a0, bfr[0], acc0, 0, 0, 0);
    acc0 = __builtin_amdgcn_mfma_f32_16x16x32_bf16(a1, bfr[1], acc0, 0, 0, 0);
    acc1 = __builtin_amdgcn_mfma_f32_16x16x32_bf16(a0, bfr[2], acc1, 0, 0, 0);
    acc1 = __builtin_amdgcn_mfma_f32_16x16x32_bf16(a1, bfr[3], acc1, 0, 0, 0);
    acc2 = __builtin_amdgcn_mfma_f32_16x16x32_bf16(a0, bfr[4], acc2, 0, 0, 0);
    acc2 = __builtin_amdgcn_mfma_f32_16x16x32_bf16(a1, bfr[5], acc2, 0, 0, 0);
    acc3 = __builtin_amdgcn_mfma_f32_16x16x32_bf16(a0, bfr[6], acc3, 0, 0, 0);
    acc3 = __builtin_amdgcn_mfma_f32_16x16x32_bf16(a1, bfr[7], acc3, 0, 0, 0);

    float* yrow = yb + (size_t)(r0 + qq * 4) * CH + c4;
#define DO_CT(CT, ACC)                                                              \
    {                                                                               \
        yrow[0 * CH + CT * 16] = ACC[0];                                            \
        yrow[1 * CH + CT * 16] = ACC[1];                                            \
        yrow[2 * CH + CT * 16] = ACC[2];                                            \
        yrow[3 * CH + CT * 16] = ACC[3];                                            \
        float s1 = (ACC[0] + ACC[1]) + (ACC[2] + ACC[3]);                           \
        float s2 = (ACC[0]*ACC[0] + ACC[1]*ACC[1]) + (ACC[2]*ACC[2] + ACC[3]*ACC[3]); \
        s1 += __shfl_xor(s1, 16); s1 += __shfl_xor(s1, 32);                         \
        s2 += __shfl_xor(s2, 16); s2 += __shfl_xor(s2, 32);                         \
        if (lane < 16) {                                                            \
            atomicAdd(&bs1[CT * 16 + lane], s1);                                    \
            atomicAdd(&bs2[CT * 16 + lane], s2);                                    \
        }                                                                           \
    }
    DO_CT(0, acc0) DO_CT(1, acc1) DO_CT(2, acc2) DO_CT(3, acc3)
#undef DO_CT

    __syncthreads();
    if (threadIdx.x < 64)        atomicAdd(&stats[threadIdx.x], bs1[threadIdx.x]);
    else if (threadIdx.x < 128)  atomicAdd(&stats[threadIdx.x], bs2[threadIdx.x - 64]);
}

// fallback normalize: in-place on f32 y, stats[128] source
__global__ __launch_bounds__(256)
void k_norm_f32(float* __restrict__ y, const float* __restrict__ stats,
                const float* __restrict__ gamma, const float* __restrict__ beta)
{
    __shared__ float s[CH], b[CH];
    if (threadIdx.x < CH) {
        const int l = threadIdx.x;
        const float inv_n = 1.0f / (float)ROWS;
        float mean = stats[l] * inv_n;
        float var  = stats[64 + l] * inv_n - mean * mean;
        float sc   = gamma[l] * rsqrtf(var + EPS);
        s[l] = sc;
        b[l] = beta[l] - mean * sc;
    }
    __syncthreads();

    f32x4* p = (f32x4*)y;
    const size_t ntot = (size_t)ROWS * CH / 4;
    size_t i = (size_t)blockIdx.x * blockDim.x + threadIdx.x;
    const size_t stride = (size_t)gridDim.x * blockDim.x;
    for (; i < ntot; i += stride) {
        f32x4 v = p[i];
        const int c0 = ((int)i & 15) * 4;
        v[0] = fmaf(v[0], s[c0],     b[c0]);
        v[1] = fmaf(v[1], s[c0 + 1], b[c0 + 1]);
        v[2] = fmaf(v[2], s[c0 + 2], b[c0 + 2]);
        v[3] = fmaf(v[3], s[c0 + 3], b[c0 + 3]);
        p[i] = v;
    }
}

extern "C" void kernel_launch(void* const* d_in, const int* in_sizes, int n_in,
                              void* d_out, int out_size, void* d_ws, size_t ws_size,
                              hipStream_t stream)
{
    const float* x     = (const float*)d_in[0];
    const int*   idx   = (const int*)d_in[1];
    const float* W     = (const float*)d_in[2];
    const float* gamma = (const float*)d_in[3];
    const float* beta  = (const float*)d_in[4];

    float*    y       = (float*)d_out;
    float*    stats   = (float*)d_ws;                     // fallback only
    unsigned* wsb     = (unsigned*)(stats + 256);         // 8KB B-fragments
    char*     base    = (char*)d_ws + 16384;
    unsigned* xb16    = (unsigned*)base;                                 // 16.8MB
    float*    stats16 = (float*)(base + (size_t)ROWS * CH * 2);          // 8KB
    unsigned* yp      = (unsigned*)(stats16 + NBUCK * 128);              // 16.8MB

    const size_t need = 16384 + (size_t)ROWS * CH * 2
                      + (size_t)NBUCK * 128 * 4 + (size_t)ROWS * CH * 2;

    if (ws_size >= need) {
        k_cvt<<<dim3(2048), dim3(256), 0, stream>>>(x, xb16, W, wsb, stats16);
        k_fused_bf16<<<dim3(NBLK), dim3(256), 0, stream>>>(xb16, idx, wsb, yp, stats16);
        k_norm_bf16<<<dim3(2048), dim3(256), 0, stream>>>(yp, y, stats16, gamma, beta);
    } else {
        k_prep_fb<<<dim3(1), dim3(64), 0, stream>>>(W, wsb, stats);
        k_fused_f32<<<dim3(2048), dim3(256), 0, stream>>>(x, idx, wsb, y, stats);
        k_norm_f32<<<dim3(2048), dim3(256), 0, stream>>>(y, stats, gamma, beta);
    }
}